// Round 10
// baseline (525.755 us; speedup 1.0000x reference)
//
#include <hip/hip_runtime.h>
#include <math.h>

#define N_NODES 100000
#define N_EDGES 1600000
#define N_GRAPHS 256
#define IN_F 64
#define H_F 128
#define GN_EPS 1e-5f
#define PAD 64
#define NBINS 8
#define LCAP 512
#define BINCAP (1 << 18)
#define SUBB 16
#define SUBW 782   // ceil(12500/16)

typedef __attribute__((ext_vector_type(8))) short bf16x8;
typedef __attribute__((ext_vector_type(4))) float f32x4;

__device__ __forceinline__ float bf2f(unsigned short u) {
  return __uint_as_float(((unsigned int)u) << 16);
}
__device__ __forceinline__ unsigned short f2bf(float f) {
  unsigned int u = __float_as_uint(f);
  u += 0x7FFFu + ((u >> 16) & 1u);
  return (unsigned short)(u >> 16);
}

// ---- cast x to bf16 (RTNE) ----
__global__ __launch_bounds__(256) void k_cast(const float4* __restrict__ in,
                                              ushort4* __restrict__ out, int n4) {
  int i = blockIdx.x * 256 + threadIdx.x;
  if (i < n4) {
    float4 v = in[i];
    ushort4 o;
    o.x = f2bf(v.x); o.y = f2bf(v.y); o.z = f2bf(v.z); o.w = f2bf(v.w);
    out[i] = o;
  }
}

// ---- pre-transpose weights to bf16 Wt[n][k] ----
__global__ __launch_bounds__(256) void k_prepW(
    const float* __restrict__ W1, const float* __restrict__ W2,
    const float* __restrict__ W3, unsigned short* __restrict__ wt) {
  int i = blockIdx.x * 256 + threadIdx.x;
  if (i < 8192) {                            // Wt1 [128][64]
    int n = i >> 6, k = i & 63;
    wt[i] = f2bf(W1[(size_t)k * H_F + n]);
  } else if (i < 24576) {                    // Wt2 [128][128]
    int j = i - 8192;
    int n = j >> 7, k = j & 127;
    wt[i] = f2bf(W2[(size_t)k * H_F + n]);
  } else if (i < 40960) {                    // Wt3 [128][128]
    int j = i - 24576;
    int n = j >> 7, k = j & 127;
    wt[i] = f2bf(W3[(size_t)k * H_F + n]);
  }
}

// ---- phase A: radix partition edges into 8 dst-range bins; u32-packed ----
// entry = (dloc<<17) | src ; dloc = d - p*12500 (<2^14), src < 2^17
__global__ __launch_bounds__(256) void k_bin(
    const int* __restrict__ src, const int* __restrict__ dst,
    unsigned int* __restrict__ binBuf, int* __restrict__ gbc) {
  __shared__ unsigned int ebuf[NBINS][LCAP];   // 16 KB
  __shared__ int lcnt[NBINS];
  __shared__ int lbase[NBINS];
  const int t = threadIdx.x;
  if (t < NBINS) lcnt[t] = 0;
  __syncthreads();
  for (int e0 = blockIdx.x * 256; e0 < N_EDGES; e0 += gridDim.x * 256) {
    int e = e0 + t;
    if (e < N_EDGES) {
      int s = src[e], d = dst[e];
      int b = d / 12500;
      int p = atomicAdd(&lcnt[b], 1);
      ebuf[b][p] = ((unsigned)(d - b * 12500) << 17) | (unsigned)s;
    }
    __syncthreads();
    if (t < NBINS && lcnt[t] >= 256) lbase[t] = atomicAdd(&gbc[t], lcnt[t]);
    __syncthreads();
#pragma unroll
    for (int b = 0; b < NBINS; ++b) {
      int c = lcnt[b];
      if (c >= 256) {
        unsigned int* gp = binBuf + (size_t)b * BINCAP + lbase[b];
        for (int i = t; i < c; i += 256) gp[i] = ebuf[b][i];
      }
    }
    __syncthreads();
    if (t < NBINS && lcnt[t] >= 256) lcnt[t] = 0;
    __syncthreads();
  }
  if (t < NBINS && lcnt[t] > 0) lbase[t] = atomicAdd(&gbc[t], lcnt[t]);
  __syncthreads();
#pragma unroll
  for (int b = 0; b < NBINS; ++b) {
    int c = lcnt[b];
    if (c > 0) {
      unsigned int* gp = binBuf + (size_t)b * BINCAP + lbase[b];
      for (int i = t; i < c; i += 256) gp[i] = ebuf[b][i];
    }
  }
}

// ---- phase B: sub-bin fill with LDS counters (no global atomics hot path) ----
// block: p = bid&7 (XCD = parent bin), s = bid>>3 (dst sub-range of 782)
__global__ __launch_bounds__(256) void k_fill3(
    const unsigned int* __restrict__ binBuf, const int* __restrict__ gbc,
    int* __restrict__ csr, int* __restrict__ cnt,
    int* __restrict__ ovfc, int* __restrict__ ovf) {
  __shared__ int lcnt[SUBW];
  const int t = threadIdx.x;
  const int p = blockIdx.x & 7;
  const int s = blockIdx.x >> 3;
  const int base = s * SUBW;
  for (int j = t; j < SUBW; j += 256) lcnt[j] = 0;
  __syncthreads();
  const int nb = gbc[p];
  const unsigned int* buf = binBuf + (size_t)p * BINCAP;
  for (int i = t; i < nb; i += 256) {
    unsigned int e = buf[i];
    int rel = (int)(e >> 17) - base;
    if ((unsigned)rel < (unsigned)SUBW) {
      int srcId = (int)(e & 131071u);
      int pos = atomicAdd(&lcnt[rel], 1);
      int d = p * 12500 + base + rel;
      if (pos < PAD) {
        csr[(size_t)d * PAD + pos] = srcId;
      } else {
        int o = atomicAdd(ovfc, 1);
        ovf[2 * o] = srcId;
        ovf[2 * o + 1] = d;
      }
    }
  }
  __syncthreads();
  for (int j = t; j < SUBW; j += 256) {
    if (base + j < 12500) {                 // stay inside parent bin's dst range
      int d = p * 12500 + base + j;
      if (d < N_NODES) cnt[d] = lcnt[j];
    }
  }
}

// ---- gather: xa = x + sum_neighbors, bf16 out ----
__global__ __launch_bounds__(256) void k_gather(
    const unsigned short* __restrict__ xh, const int* __restrict__ csr,
    const int* __restrict__ cnt, unsigned short* __restrict__ xa) {
  int wid = (blockIdx.x * 256 + threadIdx.x) >> 6;
  if (wid >= N_NODES) return;
  const int lane = threadIdx.x & 63;
  const int g = lane >> 4;
  const int fl = lane & 15;
  int deg = cnt[wid];
  if (deg > PAD) deg = PAD;
  int myE = csr[(size_t)wid * PAD + lane];
  float s0 = 0.f, s1 = 0.f, s2 = 0.f, s3 = 0.f;
  int j = g;
  for (; j + 4 < deg; j += 8) {
    int sA = __shfl(myE, j);
    int sB = __shfl(myE, j + 4);
    ushort4 a = *(const ushort4*)&xh[(size_t)sA * IN_F + fl * 4];
    ushort4 b = *(const ushort4*)&xh[(size_t)sB * IN_F + fl * 4];
    s0 += bf2f(a.x) + bf2f(b.x);
    s1 += bf2f(a.y) + bf2f(b.y);
    s2 += bf2f(a.z) + bf2f(b.z);
    s3 += bf2f(a.w) + bf2f(b.w);
  }
  if (j < deg) {
    int sA = __shfl(myE, j);
    ushort4 a = *(const ushort4*)&xh[(size_t)sA * IN_F + fl * 4];
    s0 += bf2f(a.x); s1 += bf2f(a.y); s2 += bf2f(a.z); s3 += bf2f(a.w);
  }
  s0 += __shfl_xor(s0, 16); s1 += __shfl_xor(s1, 16);
  s2 += __shfl_xor(s2, 16); s3 += __shfl_xor(s3, 16);
  s0 += __shfl_xor(s0, 32); s1 += __shfl_xor(s1, 32);
  s2 += __shfl_xor(s2, 32); s3 += __shfl_xor(s3, 32);
  if (g == 0) {
    ushort4 self = *(const ushort4*)&xh[(size_t)wid * IN_F + fl * 4];
    s0 += bf2f(self.x); s1 += bf2f(self.y);
    s2 += bf2f(self.z); s3 += bf2f(self.w);
    ushort4 r;
    r.x = f2bf(s0); r.y = f2bf(s1); r.z = f2bf(s2); r.w = f2bf(s3);
    *(ushort4*)&xa[(size_t)wid * IN_F + fl * 4] = r;
  }
}

// ---- overflow fixup (deg > PAD; expected n==0); lane = feature, race-free ----
__global__ __launch_bounds__(64) void k_ovf2(
    const int* __restrict__ ovf, const int* __restrict__ ovfc,
    const float* __restrict__ x, unsigned short* __restrict__ xa) {
  int n = *ovfc;
  int f = threadIdx.x;
  for (int o = 0; o < n; ++o) {
    int s = ovf[2 * o], d = ovf[2 * o + 1];
    size_t idx = (size_t)d * IN_F + f;
    xa[idx] = f2bf(bf2f(xa[idx]) + x[(size_t)s * IN_F + f]);
  }
}

// ========== MFMA GEMM: LDS-free, 4 waves x 32 rows (2 row-tiles share B) ==========
// C/D layout for mfma_f32_16x16x32_bf16: col = lane&15, row = (lane>>4)*4 + reg.
template <int K, int OUTF32>
__global__ __launch_bounds__(256) void k_mfma(
    const unsigned short* __restrict__ A,
    const unsigned short* __restrict__ Wt,
    const float* __restrict__ bias,
    unsigned short* __restrict__ outh,
    float* __restrict__ outf) {
  const int t = threadIdx.x;
  const int lane = t & 63;
  const int wv = t >> 6;
  const int row16 = lane & 15;
  const int kg = lane >> 4;          // 0..3
  const int NS = K / 32;
  const long r0 = (long)blockIdx.x * 128 + wv * 32;
  long arow0 = r0 + row16;       if (arow0 > N_NODES - 1) arow0 = N_NODES - 1;
  long arow1 = r0 + 16 + row16;  if (arow1 > N_NODES - 1) arow1 = N_NODES - 1;
  bf16x8 a0[K / 32], a1[K / 32];
  {
    const unsigned short* ap0 = A + arow0 * K + kg * 8;
    const unsigned short* ap1 = A + arow1 * K + kg * 8;
#pragma unroll
    for (int s = 0; s < NS; ++s) {
      a0[s] = *(const bf16x8*)(ap0 + s * 32);
      a1[s] = *(const bf16x8*)(ap1 + s * 32);
    }
  }
  f32x4 acc0[8], acc1[8];
#pragma unroll
  for (int n = 0; n < 8; ++n) {
    acc0[n] = (f32x4){0.f, 0.f, 0.f, 0.f};
    acc1[n] = (f32x4){0.f, 0.f, 0.f, 0.f};
  }
  const unsigned short* wp = Wt + (size_t)row16 * K + kg * 8;
#pragma unroll
  for (int n = 0; n < 8; ++n) {
    const unsigned short* wpn = wp + (size_t)n * 16 * K;
    bf16x8 b[K / 32];
#pragma unroll
    for (int s = 0; s < NS; ++s) b[s] = *(const bf16x8*)(wpn + s * 32);
#pragma unroll
    for (int s = 0; s < NS; ++s) {
      acc0[n] = __builtin_amdgcn_mfma_f32_16x16x32_bf16(a0[s], b[s], acc0[n], 0, 0, 0);
      acc1[n] = __builtin_amdgcn_mfma_f32_16x16x32_bf16(a1[s], b[s], acc1[n], 0, 0, 0);
    }
  }
#pragma unroll
  for (int n = 0; n < 8; ++n) {
    int col = n * 16 + row16;
    float bv = bias[col];
#pragma unroll
    for (int r = 0; r < 4; ++r) {
      long row0 = r0 + kg * 4 + r;
      long row1 = r0 + 16 + kg * 4 + r;
      if (row0 < N_NODES) {
        float v = fmaxf(acc0[n][r] + bv, 0.f);
        if (OUTF32) outf[row0 * H_F + col] = v;
        else        outh[row0 * H_F + col] = f2bf(v);
      }
      if (row1 < N_NODES) {
        float v = fmaxf(acc1[n][r] + bv, 0.f);
        if (OUTF32) outf[row1 * H_F + col] = v;
        else        outh[row1 * H_F + col] = f2bf(v);
      }
    }
  }
}

// ---- standalone GraphNorm stats over h3 fp32 (32-row blocks) ----
__global__ __launch_bounds__(256) void k_stats(
    const float* __restrict__ h, const int* __restrict__ batch,
    float* __restrict__ gsum, float* __restrict__ gsumsq) {
  __shared__ __align__(16) float4 sred[256];
  __shared__ __align__(16) float4 qred[256];
  const int t = threadIdx.x;
  const int m0 = blockIdx.x * 32;
  const int tm0 = (t >> 5) * 4, tn0 = (t & 31) * 4;
  const int rg = t >> 5, fq = t & 31;
  float4 v[4];
#pragma unroll
  for (int i = 0; i < 4; ++i)
    v[i] = *(const float4*)&h[(size_t)(m0 + tm0 + i) * H_F + tn0];
  const int glo = batch[m0];
  const int ghi = batch[m0 + 31];
  if (glo == ghi) {
    float4 s = {0,0,0,0}, q = {0,0,0,0};
#pragma unroll
    for (int i = 0; i < 4; ++i) {
      s.x += v[i].x; s.y += v[i].y; s.z += v[i].z; s.w += v[i].w;
      q.x += v[i].x * v[i].x; q.y += v[i].y * v[i].y;
      q.z += v[i].z * v[i].z; q.w += v[i].w * v[i].w;
    }
    sred[rg * 32 + fq] = s;
    qred[rg * 32 + fq] = q;
    __syncthreads();
    if (rg == 0) {
      float4 S = {0,0,0,0}, Q = {0,0,0,0};
#pragma unroll
      for (int j = 0; j < 8; ++j) {
        float4 a0 = sred[j * 32 + fq], b0 = qred[j * 32 + fq];
        S.x += a0.x; S.y += a0.y; S.z += a0.z; S.w += a0.w;
        Q.x += b0.x; Q.y += b0.y; Q.z += b0.z; Q.w += b0.w;
      }
      float* ps = &gsum[(size_t)glo * H_F + fq * 4];
      float* pq = &gsumsq[(size_t)glo * H_F + fq * 4];
      unsafeAtomicAdd(ps + 0, S.x); unsafeAtomicAdd(ps + 1, S.y);
      unsafeAtomicAdd(ps + 2, S.z); unsafeAtomicAdd(ps + 3, S.w);
      unsafeAtomicAdd(pq + 0, Q.x); unsafeAtomicAdd(pq + 1, Q.y);
      unsafeAtomicAdd(pq + 2, Q.z); unsafeAtomicAdd(pq + 3, Q.w);
    }
  } else {
    int gcur = batch[m0 + tm0];
    float4 s = {0,0,0,0}, q = {0,0,0,0};
#pragma unroll
    for (int i = 0; i < 4; ++i) {
      int g = batch[m0 + tm0 + i];
      if (g != gcur) {
        float* ps = &gsum[(size_t)gcur * H_F + tn0];
        float* pq = &gsumsq[(size_t)gcur * H_F + tn0];
        unsafeAtomicAdd(ps + 0, s.x); unsafeAtomicAdd(ps + 1, s.y);
        unsafeAtomicAdd(ps + 2, s.z); unsafeAtomicAdd(ps + 3, s.w);
        unsafeAtomicAdd(pq + 0, q.x); unsafeAtomicAdd(pq + 1, q.y);
        unsafeAtomicAdd(pq + 2, q.z); unsafeAtomicAdd(pq + 3, q.w);
        s = make_float4(0, 0, 0, 0); q = make_float4(0, 0, 0, 0);
        gcur = g;
      }
      s.x += v[i].x; s.y += v[i].y; s.z += v[i].z; s.w += v[i].w;
      q.x += v[i].x * v[i].x; q.y += v[i].y * v[i].y;
      q.z += v[i].z * v[i].z; q.w += v[i].w * v[i].w;
    }
    float* ps = &gsum[(size_t)gcur * H_F + tn0];
    float* pq = &gsumsq[(size_t)gcur * H_F + tn0];
    unsafeAtomicAdd(ps + 0, s.x); unsafeAtomicAdd(ps + 1, s.y);
    unsafeAtomicAdd(ps + 2, s.z); unsafeAtomicAdd(ps + 3, s.w);
    unsafeAtomicAdd(pq + 0, q.x); unsafeAtomicAdd(pq + 1, q.y);
    unsafeAtomicAdd(pq + 2, q.z); unsafeAtomicAdd(pq + 3, q.w);
  }
}

// ---- finalize: per (graph,feature) shift/scale; init flat = -INF ----
__global__ __launch_bounds__(128) void k_finalize(
    const int* __restrict__ batch, const float* __restrict__ gsum,
    const float* __restrict__ gsumsq, const float* __restrict__ gms,
    const float* __restrict__ gw, float* __restrict__ msc,
    float* __restrict__ scale, float* __restrict__ flat) {
  const int g = blockIdx.x;
  const int f = threadIdx.x;
  __shared__ int sb[2];
  if (f < 2) {
    int target = g + f;
    int lo = 0, hi = N_NODES;
    while (lo < hi) { int mid = (lo + hi) >> 1; if (batch[mid] < target) lo = mid + 1; else hi = mid; }
    sb[f] = lo;
  }
  __syncthreads();
  float c = fmaxf((float)(sb[1] - sb[0]), 1.0f);
  float mean = gsum[(size_t)g * H_F + f] / c;
  float ms = mean * gms[f];
  float var = gsumsq[(size_t)g * H_F + f] / c - 2.0f * ms * mean + ms * ms;
  var = fmaxf(var, 0.0f);
  msc[(size_t)g * H_F + f] = ms;
  scale[(size_t)g * H_F + f] = gw[f] * rsqrtf(var + GN_EPS);
  flat[(size_t)g * H_F + f] = -INFINITY;
}

// ---- apply: h = relu((h - msc)*scale + gb); flat = segment max ----
__global__ __launch_bounds__(256) void k_apply(
    float* __restrict__ h, const int* __restrict__ batch,
    const float* __restrict__ msc, const float* __restrict__ scale,
    const float* __restrict__ gb, float* __restrict__ flat) {
  const int t = threadIdx.x;
  const int rg = t >> 5, fq = t & 31;
  const int m0 = blockIdx.x * 32;
  const int r0 = m0 + rg * 4;
  const float4 bb = *(const float4*)&gb[fq * 4];
  const int glo = batch[m0], ghi = batch[m0 + 31];
  __shared__ __align__(16) float4 mred[8][32];
  if (glo == ghi) {
    const float4 m = *(const float4*)&msc[(size_t)glo * H_F + fq * 4];
    const float4 sc = *(const float4*)&scale[(size_t)glo * H_F + fq * 4];
    float4 mx = {-INFINITY, -INFINITY, -INFINITY, -INFINITY};
#pragma unroll
    for (int i = 0; i < 4; ++i) {
      size_t idx = (size_t)(r0 + i) * H_F + fq * 4;
      float4 v = *(const float4*)&h[idx];
      v.x = fmaxf((v.x - m.x) * sc.x + bb.x, 0.f);
      v.y = fmaxf((v.y - m.y) * sc.y + bb.y, 0.f);
      v.z = fmaxf((v.z - m.z) * sc.z + bb.z, 0.f);
      v.w = fmaxf((v.w - m.w) * sc.w + bb.w, 0.f);
      *(float4*)&h[idx] = v;
      mx.x = fmaxf(mx.x, v.x); mx.y = fmaxf(mx.y, v.y);
      mx.z = fmaxf(mx.z, v.z); mx.w = fmaxf(mx.w, v.w);
    }
    mred[rg][fq] = mx;
    __syncthreads();
    if (rg == 0) {
#pragma unroll
      for (int j = 1; j < 8; ++j) {
        float4 a = mred[j][fq];
        mx.x = fmaxf(mx.x, a.x); mx.y = fmaxf(mx.y, a.y);
        mx.z = fmaxf(mx.z, a.z); mx.w = fmaxf(mx.w, a.w);
      }
      int* pf = (int*)&flat[(size_t)glo * H_F + fq * 4];
      atomicMax(pf + 0, __float_as_int(mx.x));
      atomicMax(pf + 1, __float_as_int(mx.y));
      atomicMax(pf + 2, __float_as_int(mx.z));
      atomicMax(pf + 3, __float_as_int(mx.w));
    }
  } else {
    int gcur = batch[r0];
    float4 mm = *(const float4*)&msc[(size_t)gcur * H_F + fq * 4];
    float4 ss = *(const float4*)&scale[(size_t)gcur * H_F + fq * 4];
    float4 mx = {-INFINITY, -INFINITY, -INFINITY, -INFINITY};
#pragma unroll
    for (int i = 0; i < 4; ++i) {
      int g = batch[r0 + i];
      if (g != gcur) {
        int* pf = (int*)&flat[(size_t)gcur * H_F + fq * 4];
        atomicMax(pf + 0, __float_as_int(mx.x));
        atomicMax(pf + 1, __float_as_int(mx.y));
        atomicMax(pf + 2, __float_as_int(mx.z));
        atomicMax(pf + 3, __float_as_int(mx.w));
        mx = make_float4(-INFINITY, -INFINITY, -INFINITY, -INFINITY);
        gcur = g;
        mm = *(const float4*)&msc[(size_t)gcur * H_F + fq * 4];
        ss = *(const float4*)&scale[(size_t)gcur * H_F + fq * 4];
      }
      size_t idx = (size_t)(r0 + i) * H_F + fq * 4;
      float4 v = *(const float4*)&h[idx];
      v.x = fmaxf((v.x - mm.x) * ss.x + bb.x, 0.f);
      v.y = fmaxf((v.y - mm.y) * ss.y + bb.y, 0.f);
      v.z = fmaxf((v.z - mm.z) * ss.z + bb.z, 0.f);
      v.w = fmaxf((v.w - mm.w) * ss.w + bb.w, 0.f);
      *(float4*)&h[idx] = v;
      mx.x = fmaxf(mx.x, v.x); mx.y = fmaxf(mx.y, v.y);
      mx.z = fmaxf(mx.z, v.z); mx.w = fmaxf(mx.w, v.w);
    }
    int* pf = (int*)&flat[(size_t)gcur * H_F + fq * 4];
    atomicMax(pf + 0, __float_as_int(mx.x));
    atomicMax(pf + 1, __float_as_int(mx.y));
    atomicMax(pf + 2, __float_as_int(mx.z));
    atomicMax(pf + 3, __float_as_int(mx.w));
    __syncthreads();
  }
}

// ---------------- passthrough copies ----------------
__global__ __launch_bounds__(256) void k_copy_i2f4(const int4* __restrict__ in,
                                                   float4* __restrict__ out, int n4) {
  int i = blockIdx.x * 256 + threadIdx.x;
  if (i < n4) {
    int4 v = in[i];
    out[i] = make_float4((float)v.x, (float)v.y, (float)v.z, (float)v.w);
  }
}
__global__ __launch_bounds__(256) void k_copy_f4(const float4* __restrict__ in,
                                                 float4* __restrict__ out, int n4) {
  int i = blockIdx.x * 256 + threadIdx.x;
  if (i < n4) out[i] = in[i];
}

extern "C" void kernel_launch(void* const* d_in, const int* in_sizes, int n_in,
                              void* d_out, int out_size, void* d_ws, size_t ws_size,
                              hipStream_t stream) {
  const float* inputs = (const float*)d_in[0];
  const int*   ei     = (const int*)d_in[1];
  const int*   batch  = (const int*)d_in[2];
  const float* eattr  = (const float*)d_in[3];
  const float* W1 = (const float*)d_in[4];
  const float* b1 = (const float*)d_in[5];
  const float* W2 = (const float*)d_in[6];
  const float* b2 = (const float*)d_in[7];
  const float* W3 = (const float*)d_in[8];
  const float* b3 = (const float*)d_in[9];
  const float* gw  = (const float*)d_in[10];
  const float* gb  = (const float*)d_in[11];
  const float* gms = (const float*)d_in[12];

  float* out = (float*)d_out;
  float* hemb  = out;                          // [100000,128] fp32
  float* flat  = out + 12800000;               // [256,128]
  float* o_ei  = out + 12832768;               // [2,1600000]
  float* o_ea  = out + 16032768;               // [1600000,8]
  float* o_b   = out + 28832768;               // [100000]

  // Scratch (all dead before their region is finally written):
  //  hemb region: binBuf u32 8MB @0, xh bf16 @4.2M floats, xa bf16 @7.6M floats
  //  o_ea region: csr @0 (25.6MB) -> h2 bf16 after gather; h1 bf16 @6.4M floats
  //  o_ei region: cnt/ovfc/gbc/ovf + gsum/gsumq/msc/scl + Wt bf16
  unsigned int*   binBuf = (unsigned int*)hemb;
  unsigned short* xh = (unsigned short*)(hemb + 4200000);
  unsigned short* xa = (unsigned short*)(hemb + 7600000);
  int*            csr = (int*)o_ea;
  unsigned short* h2  = (unsigned short*)o_ea;
  unsigned short* h1  = (unsigned short*)(o_ea + 6400000);
  int*   cnt   = (int*)o_ei;
  int*   ovfc  = (int*)o_ei + 100000;
  int*   gbc   = (int*)o_ei + 100008;
  int*   ovf   = (int*)o_ei + 100032;
  float* gsum  = o_ei + 200000;
  float* gsumq = o_ei + 232768;
  float* msc   = o_ei + 265536;
  float* scl   = o_ei + 298304;
  unsigned short* wt  = (unsigned short*)(o_ei + 350000);
  unsigned short* wt1 = wt;
  unsigned short* wt2 = wt + 8192;
  unsigned short* wt3 = wt + 24576;

  hipMemsetAsync(ovfc, 0, 64 * sizeof(int), stream);   // ovfc + gbc (cnt handled by k_fill3)
  hipMemsetAsync(gsum, 0, 2 * N_GRAPHS * H_F * sizeof(float), stream);
  k_prepW<<<160, 256, 0, stream>>>(W1, W2, W3, wt);
  k_cast<<<(N_NODES * IN_F / 4 + 255) / 256, 256, 0, stream>>>(
      (const float4*)inputs, (ushort4*)xh, N_NODES * IN_F / 4);
  k_bin<<<512, 256, 0, stream>>>(ei, ei + N_EDGES, binBuf, gbc);
  k_fill3<<<NBINS * SUBB, 256, 0, stream>>>(binBuf, gbc, csr, cnt, ovfc, ovf);
  k_gather<<<(N_NODES * 64 + 255) / 256, 256, 0, stream>>>(xh, csr, cnt, xa);
  k_ovf2<<<1, 64, 0, stream>>>(ovf, ovfc, inputs, xa);
  const int mg = (N_NODES + 127) / 128;   // 782
  k_mfma<64, 0><<<mg, 256, 0, stream>>>(xa, wt1, b1, h1, nullptr);
  k_mfma<128, 0><<<mg, 256, 0, stream>>>(h1, wt2, b2, h2, nullptr);
  k_mfma<128, 1><<<mg, 256, 0, stream>>>(h2, wt3, b3, nullptr, hemb);
  k_stats<<<N_NODES / 32, 256, 0, stream>>>(hemb, batch, gsum, gsumq);
  k_finalize<<<N_GRAPHS, 128, 0, stream>>>(batch, gsum, gsumq, gms, gw, msc, scl, flat);
  k_apply<<<N_NODES / 32, 256, 0, stream>>>(hemb, batch, msc, scl, gb, flat);
  k_copy_i2f4<<<(2 * N_EDGES / 4 + 255) / 256, 256, 0, stream>>>((const int4*)ei, (float4*)o_ei, 2 * N_EDGES / 4);
  k_copy_f4<<<(N_EDGES * 2 + 255) / 256, 256, 0, stream>>>((const float4*)eattr, (float4*)o_ea, N_EDGES * 2);
  k_copy_i2f4<<<(N_NODES / 4 + 255) / 256, 256, 0, stream>>>((const int4*)batch, (float4*)o_b, N_NODES / 4);
}

// Round 11
// 336.507 us; speedup vs baseline: 1.5624x; 1.5624x over previous
//
#include <hip/hip_runtime.h>
#include <math.h>

#define N_NODES 100000
#define N_EDGES 1600000
#define N_GRAPHS 256
#define IN_F 64
#define H_F 128
#define GN_EPS 1e-5f
#define PAD 32
#define NBINS 8
#define LCAP 512
#define BINCAP (1 << 18)

typedef __attribute__((ext_vector_type(8))) short bf16x8;
typedef __attribute__((ext_vector_type(4))) float f32x4;

__device__ __forceinline__ float bf2f(unsigned short u) {
  return __uint_as_float(((unsigned int)u) << 16);
}
__device__ __forceinline__ unsigned short f2bf(float f) {
  unsigned int u = __float_as_uint(f);
  u += 0x7FFFu + ((u >> 16) & 1u);
  return (unsigned short)(u >> 16);
}

// ---- cast x to bf16 (RTNE) ----
__global__ __launch_bounds__(256) void k_cast(const float4* __restrict__ in,
                                              ushort4* __restrict__ out, int n4) {
  int i = blockIdx.x * 256 + threadIdx.x;
  if (i < n4) {
    float4 v = in[i];
    ushort4 o;
    o.x = f2bf(v.x); o.y = f2bf(v.y); o.z = f2bf(v.z); o.w = f2bf(v.w);
    out[i] = o;
  }
}

// ---- pre-transpose weights to bf16 Wt[n][k] ----
__global__ __launch_bounds__(256) void k_prepW(
    const float* __restrict__ W1, const float* __restrict__ W2,
    const float* __restrict__ W3, unsigned short* __restrict__ wt) {
  int i = blockIdx.x * 256 + threadIdx.x;
  if (i < 8192) {                            // Wt1 [128][64]
    int n = i >> 6, k = i & 63;
    wt[i] = f2bf(W1[(size_t)k * H_F + n]);
  } else if (i < 24576) {                    // Wt2 [128][128]
    int j = i - 8192;
    int n = j >> 7, k = j & 127;
    wt[i] = f2bf(W2[(size_t)k * H_F + n]);
  } else if (i < 40960) {                    // Wt3 [128][128]
    int j = i - 24576;
    int n = j >> 7, k = j & 127;
    wt[i] = f2bf(W3[(size_t)k * H_F + n]);
  }
}

// ---- phase A: radix partition edges into 8 dst-range bins; u32-packed ----
// entry = (dloc<<17) | src ; dloc = d - p*12500 (<2^14), src < 2^17
__global__ __launch_bounds__(256) void k_bin(
    const int* __restrict__ src, const int* __restrict__ dst,
    unsigned int* __restrict__ binBuf, int* __restrict__ gbc) {
  __shared__ unsigned int ebuf[NBINS][LCAP];   // 16 KB
  __shared__ int lcnt[NBINS];
  __shared__ int lbase[NBINS];
  const int t = threadIdx.x;
  if (t < NBINS) lcnt[t] = 0;
  __syncthreads();
  for (int e0 = blockIdx.x * 256; e0 < N_EDGES; e0 += gridDim.x * 256) {
    int e = e0 + t;
    if (e < N_EDGES) {
      int s = src[e], d = dst[e];
      int b = d / 12500;
      int p = atomicAdd(&lcnt[b], 1);
      ebuf[b][p] = ((unsigned)(d - b * 12500) << 17) | (unsigned)s;
    }
    __syncthreads();
    if (t < NBINS && lcnt[t] >= 256) lbase[t] = atomicAdd(&gbc[t], lcnt[t]);
    __syncthreads();
#pragma unroll
    for (int b = 0; b < NBINS; ++b) {
      int c = lcnt[b];
      if (c >= 256) {
        unsigned int* gp = binBuf + (size_t)b * BINCAP + lbase[b];
        for (int i = t; i < c; i += 256) gp[i] = ebuf[b][i];
      }
    }
    __syncthreads();
    if (t < NBINS && lcnt[t] >= 256) lcnt[t] = 0;
    __syncthreads();
  }
  if (t < NBINS && lcnt[t] > 0) lbase[t] = atomicAdd(&gbc[t], lcnt[t]);
  __syncthreads();
#pragma unroll
  for (int b = 0; b < NBINS; ++b) {
    int c = lcnt[b];
    if (c > 0) {
      unsigned int* gp = binBuf + (size_t)b * BINCAP + lbase[b];
      for (int i = t; i < c; i += 256) gp[i] = ebuf[b][i];
    }
  }
}

// ---- phase B: bucket fill, bin-per-XCD (bid&7), global atomics, u32 entries ----
__global__ __launch_bounds__(256) void k_fill2(
    const unsigned int* __restrict__ binBuf, const int* __restrict__ gbc,
    int* __restrict__ csr, int* __restrict__ cnt,
    int* __restrict__ ovfc, int* __restrict__ ovf) {
  const int b = blockIdx.x & 7;
  const int nb = gbc[b];
  const unsigned int* buf = binBuf + (size_t)b * BINCAP;
  const int stride = (gridDim.x >> 3) * 256;
  for (int i = (blockIdx.x >> 3) * 256 + threadIdx.x; i < nb; i += stride) {
    unsigned int e = buf[i];
    int d = b * 12500 + (int)(e >> 17);
    int s = (int)(e & 131071u);
    int pos = atomicAdd(&cnt[d], 1);
    if (pos < PAD) {
      csr[(size_t)d * PAD + pos] = s;
    } else {
      int o = atomicAdd(ovfc, 1);
      ovf[2 * o] = s;
      ovf[2 * o + 1] = d;
    }
  }
}

// ---- gather: xa = x + sum_neighbors, bf16 out; csr row = 32 ids (128 B) ----
__global__ __launch_bounds__(256) void k_gather(
    const unsigned short* __restrict__ xh, const int* __restrict__ csr,
    const int* __restrict__ cnt, unsigned short* __restrict__ xa) {
  int wid = (blockIdx.x * 256 + threadIdx.x) >> 6;
  if (wid >= N_NODES) return;
  const int lane = threadIdx.x & 63;
  const int g = lane >> 4;
  const int fl = lane & 15;
  int deg = cnt[wid];
  if (deg > PAD) deg = PAD;
  int myE = csr[(size_t)wid * PAD + (lane & 31)];
  float s0 = 0.f, s1 = 0.f, s2 = 0.f, s3 = 0.f;
  int j = g;
  for (; j + 4 < deg; j += 8) {
    int sA = __shfl(myE, j);
    int sB = __shfl(myE, j + 4);
    ushort4 a = *(const ushort4*)&xh[(size_t)sA * IN_F + fl * 4];
    ushort4 b = *(const ushort4*)&xh[(size_t)sB * IN_F + fl * 4];
    s0 += bf2f(a.x) + bf2f(b.x);
    s1 += bf2f(a.y) + bf2f(b.y);
    s2 += bf2f(a.z) + bf2f(b.z);
    s3 += bf2f(a.w) + bf2f(b.w);
  }
  if (j < deg) {
    int sA = __shfl(myE, j);
    ushort4 a = *(const ushort4*)&xh[(size_t)sA * IN_F + fl * 4];
    s0 += bf2f(a.x); s1 += bf2f(a.y); s2 += bf2f(a.z); s3 += bf2f(a.w);
  }
  s0 += __shfl_xor(s0, 16); s1 += __shfl_xor(s1, 16);
  s2 += __shfl_xor(s2, 16); s3 += __shfl_xor(s3, 16);
  s0 += __shfl_xor(s0, 32); s1 += __shfl_xor(s1, 32);
  s2 += __shfl_xor(s2, 32); s3 += __shfl_xor(s3, 32);
  if (g == 0) {
    ushort4 self = *(const ushort4*)&xh[(size_t)wid * IN_F + fl * 4];
    s0 += bf2f(self.x); s1 += bf2f(self.y);
    s2 += bf2f(self.z); s3 += bf2f(self.w);
    ushort4 r;
    r.x = f2bf(s0); r.y = f2bf(s1); r.z = f2bf(s2); r.w = f2bf(s3);
    *(ushort4*)&xa[(size_t)wid * IN_F + fl * 4] = r;
  }
}

// ---- overflow fixup (deg > PAD; expected ~0); lane = feature, race-free ----
__global__ __launch_bounds__(64) void k_ovf2(
    const int* __restrict__ ovf, const int* __restrict__ ovfc,
    const float* __restrict__ x, unsigned short* __restrict__ xa) {
  int n = *ovfc;
  int f = threadIdx.x;
  for (int o = 0; o < n; ++o) {
    int s = ovf[2 * o], d = ovf[2 * o + 1];
    size_t idx = (size_t)d * IN_F + f;
    xa[idx] = f2bf(bf2f(xa[idx]) + x[(size_t)s * IN_F + f]);
  }
}

// ========== MFMA GEMM: LDS-free, 4 waves x 32 rows (2 row-tiles share B) ==========
// C/D layout for mfma_f32_16x16x32_bf16: col = lane&15, row = (lane>>4)*4 + reg.
template <int K, int OUTF32>
__global__ __launch_bounds__(256) void k_mfma(
    const unsigned short* __restrict__ A,
    const unsigned short* __restrict__ Wt,
    const float* __restrict__ bias,
    unsigned short* __restrict__ outh,
    float* __restrict__ outf) {
  const int t = threadIdx.x;
  const int lane = t & 63;
  const int wv = t >> 6;
  const int row16 = lane & 15;
  const int kg = lane >> 4;          // 0..3
  const int NS = K / 32;
  const long r0 = (long)blockIdx.x * 128 + wv * 32;
  long arow0 = r0 + row16;       if (arow0 > N_NODES - 1) arow0 = N_NODES - 1;
  long arow1 = r0 + 16 + row16;  if (arow1 > N_NODES - 1) arow1 = N_NODES - 1;
  bf16x8 a0[K / 32], a1[K / 32];
  {
    const unsigned short* ap0 = A + arow0 * K + kg * 8;
    const unsigned short* ap1 = A + arow1 * K + kg * 8;
#pragma unroll
    for (int s = 0; s < NS; ++s) {
      a0[s] = *(const bf16x8*)(ap0 + s * 32);
      a1[s] = *(const bf16x8*)(ap1 + s * 32);
    }
  }
  f32x4 acc0[8], acc1[8];
#pragma unroll
  for (int n = 0; n < 8; ++n) {
    acc0[n] = (f32x4){0.f, 0.f, 0.f, 0.f};
    acc1[n] = (f32x4){0.f, 0.f, 0.f, 0.f};
  }
  const unsigned short* wp = Wt + (size_t)row16 * K + kg * 8;
#pragma unroll
  for (int n = 0; n < 8; ++n) {
    const unsigned short* wpn = wp + (size_t)n * 16 * K;
    bf16x8 b[K / 32];
#pragma unroll
    for (int s = 0; s < NS; ++s) b[s] = *(const bf16x8*)(wpn + s * 32);
#pragma unroll
    for (int s = 0; s < NS; ++s) {
      acc0[n] = __builtin_amdgcn_mfma_f32_16x16x32_bf16(a0[s], b[s], acc0[n], 0, 0, 0);
      acc1[n] = __builtin_amdgcn_mfma_f32_16x16x32_bf16(a1[s], b[s], acc1[n], 0, 0, 0);
    }
  }
#pragma unroll
  for (int n = 0; n < 8; ++n) {
    int col = n * 16 + row16;
    float bv = bias[col];
#pragma unroll
    for (int r = 0; r < 4; ++r) {
      long row0 = r0 + kg * 4 + r;
      long row1 = r0 + 16 + kg * 4 + r;
      if (row0 < N_NODES) {
        float v = fmaxf(acc0[n][r] + bv, 0.f);
        if (OUTF32) outf[row0 * H_F + col] = v;
        else        outh[row0 * H_F + col] = f2bf(v);
      }
      if (row1 < N_NODES) {
        float v = fmaxf(acc1[n][r] + bv, 0.f);
        if (OUTF32) outf[row1 * H_F + col] = v;
        else        outh[row1 * H_F + col] = f2bf(v);
      }
    }
  }
}

// ---- standalone GraphNorm stats over h3 fp32 (32-row blocks) ----
__global__ __launch_bounds__(256) void k_stats(
    const float* __restrict__ h, const int* __restrict__ batch,
    float* __restrict__ gsum, float* __restrict__ gsumsq) {
  __shared__ __align__(16) float4 sred[256];
  __shared__ __align__(16) float4 qred[256];
  const int t = threadIdx.x;
  const int m0 = blockIdx.x * 32;
  const int tm0 = (t >> 5) * 4, tn0 = (t & 31) * 4;
  const int rg = t >> 5, fq = t & 31;
  float4 v[4];
#pragma unroll
  for (int i = 0; i < 4; ++i)
    v[i] = *(const float4*)&h[(size_t)(m0 + tm0 + i) * H_F + tn0];
  const int glo = batch[m0];
  const int ghi = batch[m0 + 31];
  if (glo == ghi) {
    float4 s = {0,0,0,0}, q = {0,0,0,0};
#pragma unroll
    for (int i = 0; i < 4; ++i) {
      s.x += v[i].x; s.y += v[i].y; s.z += v[i].z; s.w += v[i].w;
      q.x += v[i].x * v[i].x; q.y += v[i].y * v[i].y;
      q.z += v[i].z * v[i].z; q.w += v[i].w * v[i].w;
    }
    sred[rg * 32 + fq] = s;
    qred[rg * 32 + fq] = q;
    __syncthreads();
    if (rg == 0) {
      float4 S = {0,0,0,0}, Q = {0,0,0,0};
#pragma unroll
      for (int j = 0; j < 8; ++j) {
        float4 a0 = sred[j * 32 + fq], b0 = qred[j * 32 + fq];
        S.x += a0.x; S.y += a0.y; S.z += a0.z; S.w += a0.w;
        Q.x += b0.x; Q.y += b0.y; Q.z += b0.z; Q.w += b0.w;
      }
      float* ps = &gsum[(size_t)glo * H_F + fq * 4];
      float* pq = &gsumsq[(size_t)glo * H_F + fq * 4];
      unsafeAtomicAdd(ps + 0, S.x); unsafeAtomicAdd(ps + 1, S.y);
      unsafeAtomicAdd(ps + 2, S.z); unsafeAtomicAdd(ps + 3, S.w);
      unsafeAtomicAdd(pq + 0, Q.x); unsafeAtomicAdd(pq + 1, Q.y);
      unsafeAtomicAdd(pq + 2, Q.z); unsafeAtomicAdd(pq + 3, Q.w);
    }
  } else {
    int gcur = batch[m0 + tm0];
    float4 s = {0,0,0,0}, q = {0,0,0,0};
#pragma unroll
    for (int i = 0; i < 4; ++i) {
      int g = batch[m0 + tm0 + i];
      if (g != gcur) {
        float* ps = &gsum[(size_t)gcur * H_F + tn0];
        float* pq = &gsumsq[(size_t)gcur * H_F + tn0];
        unsafeAtomicAdd(ps + 0, s.x); unsafeAtomicAdd(ps + 1, s.y);
        unsafeAtomicAdd(ps + 2, s.z); unsafeAtomicAdd(ps + 3, s.w);
        unsafeAtomicAdd(pq + 0, q.x); unsafeAtomicAdd(pq + 1, q.y);
        unsafeAtomicAdd(pq + 2, q.z); unsafeAtomicAdd(pq + 3, q.w);
        s = make_float4(0, 0, 0, 0); q = make_float4(0, 0, 0, 0);
        gcur = g;
      }
      s.x += v[i].x; s.y += v[i].y; s.z += v[i].z; s.w += v[i].w;
      q.x += v[i].x * v[i].x; q.y += v[i].y * v[i].y;
      q.z += v[i].z * v[i].z; q.w += v[i].w * v[i].w;
    }
    float* ps = &gsum[(size_t)gcur * H_F + tn0];
    float* pq = &gsumsq[(size_t)gcur * H_F + tn0];
    unsafeAtomicAdd(ps + 0, s.x); unsafeAtomicAdd(ps + 1, s.y);
    unsafeAtomicAdd(ps + 2, s.z); unsafeAtomicAdd(ps + 3, s.w);
    unsafeAtomicAdd(pq + 0, q.x); unsafeAtomicAdd(pq + 1, q.y);
    unsafeAtomicAdd(pq + 2, q.z); unsafeAtomicAdd(pq + 3, q.w);
  }
}

// ---- finalize: per (graph,feature) shift/scale; init flat = -INF ----
__global__ __launch_bounds__(128) void k_finalize(
    const int* __restrict__ batch, const float* __restrict__ gsum,
    const float* __restrict__ gsumsq, const float* __restrict__ gms,
    const float* __restrict__ gw, float* __restrict__ msc,
    float* __restrict__ scale, float* __restrict__ flat) {
  const int g = blockIdx.x;
  const int f = threadIdx.x;
  __shared__ int sb[2];
  if (f < 2) {
    int target = g + f;
    int lo = 0, hi = N_NODES;
    while (lo < hi) { int mid = (lo + hi) >> 1; if (batch[mid] < target) lo = mid + 1; else hi = mid; }
    sb[f] = lo;
  }
  __syncthreads();
  float c = fmaxf((float)(sb[1] - sb[0]), 1.0f);
  float mean = gsum[(size_t)g * H_F + f] / c;
  float ms = mean * gms[f];
  float var = gsumsq[(size_t)g * H_F + f] / c - 2.0f * ms * mean + ms * ms;
  var = fmaxf(var, 0.0f);
  msc[(size_t)g * H_F + f] = ms;
  scale[(size_t)g * H_F + f] = gw[f] * rsqrtf(var + GN_EPS);
  flat[(size_t)g * H_F + f] = -INFINITY;
}

// ---- apply: h = relu((h - msc)*scale + gb); flat = segment max ----
__global__ __launch_bounds__(256) void k_apply(
    float* __restrict__ h, const int* __restrict__ batch,
    const float* __restrict__ msc, const float* __restrict__ scale,
    const float* __restrict__ gb, float* __restrict__ flat) {
  const int t = threadIdx.x;
  const int rg = t >> 5, fq = t & 31;
  const int m0 = blockIdx.x * 32;
  const int r0 = m0 + rg * 4;
  const float4 bb = *(const float4*)&gb[fq * 4];
  const int glo = batch[m0], ghi = batch[m0 + 31];
  __shared__ __align__(16) float4 mred[8][32];
  if (glo == ghi) {
    const float4 m = *(const float4*)&msc[(size_t)glo * H_F + fq * 4];
    const float4 sc = *(const float4*)&scale[(size_t)glo * H_F + fq * 4];
    float4 mx = {-INFINITY, -INFINITY, -INFINITY, -INFINITY};
#pragma unroll
    for (int i = 0; i < 4; ++i) {
      size_t idx = (size_t)(r0 + i) * H_F + fq * 4;
      float4 v = *(const float4*)&h[idx];
      v.x = fmaxf((v.x - m.x) * sc.x + bb.x, 0.f);
      v.y = fmaxf((v.y - m.y) * sc.y + bb.y, 0.f);
      v.z = fmaxf((v.z - m.z) * sc.z + bb.z, 0.f);
      v.w = fmaxf((v.w - m.w) * sc.w + bb.w, 0.f);
      *(float4*)&h[idx] = v;
      mx.x = fmaxf(mx.x, v.x); mx.y = fmaxf(mx.y, v.y);
      mx.z = fmaxf(mx.z, v.z); mx.w = fmaxf(mx.w, v.w);
    }
    mred[rg][fq] = mx;
    __syncthreads();
    if (rg == 0) {
#pragma unroll
      for (int j = 1; j < 8; ++j) {
        float4 a = mred[j][fq];
        mx.x = fmaxf(mx.x, a.x); mx.y = fmaxf(mx.y, a.y);
        mx.z = fmaxf(mx.z, a.z); mx.w = fmaxf(mx.w, a.w);
      }
      int* pf = (int*)&flat[(size_t)glo * H_F + fq * 4];
      atomicMax(pf + 0, __float_as_int(mx.x));
      atomicMax(pf + 1, __float_as_int(mx.y));
      atomicMax(pf + 2, __float_as_int(mx.z));
      atomicMax(pf + 3, __float_as_int(mx.w));
    }
  } else {
    int gcur = batch[r0];
    float4 mm = *(const float4*)&msc[(size_t)gcur * H_F + fq * 4];
    float4 ss = *(const float4*)&scale[(size_t)gcur * H_F + fq * 4];
    float4 mx = {-INFINITY, -INFINITY, -INFINITY, -INFINITY};
#pragma unroll
    for (int i = 0; i < 4; ++i) {
      int g = batch[r0 + i];
      if (g != gcur) {
        int* pf = (int*)&flat[(size_t)gcur * H_F + fq * 4];
        atomicMax(pf + 0, __float_as_int(mx.x));
        atomicMax(pf + 1, __float_as_int(mx.y));
        atomicMax(pf + 2, __float_as_int(mx.z));
        atomicMax(pf + 3, __float_as_int(mx.w));
        mx = make_float4(-INFINITY, -INFINITY, -INFINITY, -INFINITY);
        gcur = g;
        mm = *(const float4*)&msc[(size_t)gcur * H_F + fq * 4];
        ss = *(const float4*)&scale[(size_t)gcur * H_F + fq * 4];
      }
      size_t idx = (size_t)(r0 + i) * H_F + fq * 4;
      float4 v = *(const float4*)&h[idx];
      v.x = fmaxf((v.x - mm.x) * ss.x + bb.x, 0.f);
      v.y = fmaxf((v.y - mm.y) * ss.y + bb.y, 0.f);
      v.z = fmaxf((v.z - mm.z) * ss.z + bb.z, 0.f);
      v.w = fmaxf((v.w - mm.w) * ss.w + bb.w, 0.f);
      *(float4*)&h[idx] = v;
      mx.x = fmaxf(mx.x, v.x); mx.y = fmaxf(mx.y, v.y);
      mx.z = fmaxf(mx.z, v.z); mx.w = fmaxf(mx.w, v.w);
    }
    int* pf = (int*)&flat[(size_t)gcur * H_F + fq * 4];
    atomicMax(pf + 0, __float_as_int(mx.x));
    atomicMax(pf + 1, __float_as_int(mx.y));
    atomicMax(pf + 2, __float_as_int(mx.z));
    atomicMax(pf + 3, __float_as_int(mx.w));
    __syncthreads();
  }
}

// ---------------- passthrough copies ----------------
__global__ __launch_bounds__(256) void k_copy_i2f4(const int4* __restrict__ in,
                                                   float4* __restrict__ out, int n4) {
  int i = blockIdx.x * 256 + threadIdx.x;
  if (i < n4) {
    int4 v = in[i];
    out[i] = make_float4((float)v.x, (float)v.y, (float)v.z, (float)v.w);
  }
}
__global__ __launch_bounds__(256) void k_copy_f4(const float4* __restrict__ in,
                                                 float4* __restrict__ out, int n4) {
  int i = blockIdx.x * 256 + threadIdx.x;
  if (i < n4) out[i] = in[i];
}

extern "C" void kernel_launch(void* const* d_in, const int* in_sizes, int n_in,
                              void* d_out, int out_size, void* d_ws, size_t ws_size,
                              hipStream_t stream) {
  const float* inputs = (const float*)d_in[0];
  const int*   ei     = (const int*)d_in[1];
  const int*   batch  = (const int*)d_in[2];
  const float* eattr  = (const float*)d_in[3];
  const float* W1 = (const float*)d_in[4];
  const float* b1 = (const float*)d_in[5];
  const float* W2 = (const float*)d_in[6];
  const float* b2 = (const float*)d_in[7];
  const float* W3 = (const float*)d_in[8];
  const float* b3 = (const float*)d_in[9];
  const float* gw  = (const float*)d_in[10];
  const float* gb  = (const float*)d_in[11];
  const float* gms = (const float*)d_in[12];

  float* out = (float*)d_out;
  float* hemb  = out;                          // [100000,128] fp32
  float* flat  = out + 12800000;               // [256,128]
  float* o_ei  = out + 12832768;               // [2,1600000]
  float* o_ea  = out + 16032768;               // [1600000,8]
  float* o_b   = out + 28832768;               // [100000]

  // Scratch (all dead before their region is finally written):
  //  hemb region: binBuf u32 8MB @0, xh bf16 @4.2M floats, xa bf16 @7.6M floats
  //  o_ea region: csr [100000][32] ints @0 (12.8MB) -> h2 bf16 after gather;
  //               h1 bf16 @6.4M floats
  //  o_ei region: cnt/ovfc/gbc/ovf + gsum/gsumq/msc/scl + Wt bf16
  unsigned int*   binBuf = (unsigned int*)hemb;
  unsigned short* xh = (unsigned short*)(hemb + 4200000);
  unsigned short* xa = (unsigned short*)(hemb + 7600000);
  int*            csr = (int*)o_ea;
  unsigned short* h2  = (unsigned short*)o_ea;
  unsigned short* h1  = (unsigned short*)(o_ea + 6400000);
  int*   cnt   = (int*)o_ei;
  int*   ovfc  = (int*)o_ei + 100000;
  int*   gbc   = (int*)o_ei + 100008;
  int*   ovf   = (int*)o_ei + 100032;
  float* gsum  = o_ei + 200000;
  float* gsumq = o_ei + 232768;
  float* msc   = o_ei + 265536;
  float* scl   = o_ei + 298304;
  unsigned short* wt  = (unsigned short*)(o_ei + 350000);
  unsigned short* wt1 = wt;
  unsigned short* wt2 = wt + 8192;
  unsigned short* wt3 = wt + 24576;

  hipMemsetAsync(cnt, 0, (N_NODES + 64) * sizeof(int), stream);  // cnt + ovfc + gbc
  hipMemsetAsync(gsum, 0, 2 * N_GRAPHS * H_F * sizeof(float), stream);
  k_prepW<<<160, 256, 0, stream>>>(W1, W2, W3, wt);
  k_cast<<<(N_NODES * IN_F / 4 + 255) / 256, 256, 0, stream>>>(
      (const float4*)inputs, (ushort4*)xh, N_NODES * IN_F / 4);
  k_bin<<<512, 256, 0, stream>>>(ei, ei + N_EDGES, binBuf, gbc);
  k_fill2<<<8 * 160, 256, 0, stream>>>(binBuf, gbc, csr, cnt, ovfc, ovf);
  k_gather<<<(N_NODES * 64 + 255) / 256, 256, 0, stream>>>(xh, csr, cnt, xa);
  k_ovf2<<<1, 64, 0, stream>>>(ovf, ovfc, inputs, xa);
  const int mg = (N_NODES + 127) / 128;   // 782
  k_mfma<64, 0><<<mg, 256, 0, stream>>>(xa, wt1, b1, h1, nullptr);
  k_mfma<128, 0><<<mg, 256, 0, stream>>>(h1, wt2, b2, h2, nullptr);
  k_mfma<128, 1><<<mg, 256, 0, stream>>>(h2, wt3, b3, nullptr, hemb);
  k_stats<<<N_NODES / 32, 256, 0, stream>>>(hemb, batch, gsum, gsumq);
  k_finalize<<<N_GRAPHS, 128, 0, stream>>>(batch, gsum, gsumq, gms, gw, msc, scl, flat);
  k_apply<<<N_NODES / 32, 256, 0, stream>>>(hemb, batch, msc, scl, gb, flat);
  k_copy_i2f4<<<(2 * N_EDGES / 4 + 255) / 256, 256, 0, stream>>>((const int4*)ei, (float4*)o_ei, 2 * N_EDGES / 4);
  k_copy_f4<<<(N_EDGES * 2 + 255) / 256, 256, 0, stream>>>((const float4*)eattr, (float4*)o_ea, N_EDGES * 2);
  k_copy_i2f4<<<(N_NODES / 4 + 255) / 256, 256, 0, stream>>>((const int4*)batch, (float4*)o_b, N_NODES / 4);
}

// Round 12
// 333.307 us; speedup vs baseline: 1.5774x; 1.0096x over previous
//
#include <hip/hip_runtime.h>
#include <math.h>

#define N_NODES 100000
#define N_EDGES 1600000
#define N_GRAPHS 256
#define IN_F 64
#define H_F 128
#define GN_EPS 1e-5f
#define PAD 32
#define NBINS 8
#define LCAP 512
#define BINCAP (1 << 18)
#define NSUB 16
#define SUBW 782            // 16*782 = 12512 >= 12500
#define SBCAP 16384         // entries per sub-bin (expected ~12.5K)

typedef __attribute__((ext_vector_type(8))) short bf16x8;
typedef __attribute__((ext_vector_type(4))) float f32x4;

__device__ __forceinline__ float bf2f(unsigned short u) {
  return __uint_as_float(((unsigned int)u) << 16);
}
__device__ __forceinline__ unsigned short f2bf(float f) {
  unsigned int u = __float_as_uint(f);
  u += 0x7FFFu + ((u >> 16) & 1u);
  return (unsigned short)(u >> 16);
}

// ---- cast x to bf16 (RTNE) ----
__global__ __launch_bounds__(256) void k_cast(const float4* __restrict__ in,
                                              ushort4* __restrict__ out, int n4) {
  int i = blockIdx.x * 256 + threadIdx.x;
  if (i < n4) {
    float4 v = in[i];
    ushort4 o;
    o.x = f2bf(v.x); o.y = f2bf(v.y); o.z = f2bf(v.z); o.w = f2bf(v.w);
    out[i] = o;
  }
}

// ---- pre-transpose weights to bf16 Wt[n][k] ----
__global__ __launch_bounds__(256) void k_prepW(
    const float* __restrict__ W1, const float* __restrict__ W2,
    const float* __restrict__ W3, unsigned short* __restrict__ wt) {
  int i = blockIdx.x * 256 + threadIdx.x;
  if (i < 8192) {                            // Wt1 [128][64]
    int n = i >> 6, k = i & 63;
    wt[i] = f2bf(W1[(size_t)k * H_F + n]);
  } else if (i < 24576) {                    // Wt2 [128][128]
    int j = i - 8192;
    int n = j >> 7, k = j & 127;
    wt[i] = f2bf(W2[(size_t)k * H_F + n]);
  } else if (i < 40960) {                    // Wt3 [128][128]
    int j = i - 24576;
    int n = j >> 7, k = j & 127;
    wt[i] = f2bf(W3[(size_t)k * H_F + n]);
  }
}

// ---- phase A: radix partition edges into 8 dst-range bins; u32-packed ----
// entry = (dloc<<17) | src ; dloc = d - p*12500 (<2^14), src < 2^17
__global__ __launch_bounds__(256) void k_bin(
    const int* __restrict__ src, const int* __restrict__ dst,
    unsigned int* __restrict__ binBuf, int* __restrict__ gbc) {
  __shared__ unsigned int ebuf[NBINS][LCAP];   // 16 KB
  __shared__ int lcnt[NBINS];
  __shared__ int lbase[NBINS];
  const int t = threadIdx.x;
  if (t < NBINS) lcnt[t] = 0;
  __syncthreads();
  for (int e0 = blockIdx.x * 256; e0 < N_EDGES; e0 += gridDim.x * 256) {
    int e = e0 + t;
    if (e < N_EDGES) {
      int s = src[e], d = dst[e];
      int b = d / 12500;
      int p = atomicAdd(&lcnt[b], 1);
      ebuf[b][p] = ((unsigned)(d - b * 12500) << 17) | (unsigned)s;
    }
    __syncthreads();
    if (t < NBINS && lcnt[t] >= 256) lbase[t] = atomicAdd(&gbc[t], lcnt[t]);
    __syncthreads();
#pragma unroll
    for (int b = 0; b < NBINS; ++b) {
      int c = lcnt[b];
      if (c >= 256) {
        unsigned int* gp = binBuf + (size_t)b * BINCAP + lbase[b];
        for (int i = t; i < c; i += 256) gp[i] = ebuf[b][i];
      }
    }
    __syncthreads();
    if (t < NBINS && lcnt[t] >= 256) lcnt[t] = 0;
    __syncthreads();
  }
  if (t < NBINS && lcnt[t] > 0) lbase[t] = atomicAdd(&gbc[t], lcnt[t]);
  __syncthreads();
#pragma unroll
  for (int b = 0; b < NBINS; ++b) {
    int c = lcnt[b];
    if (c > 0) {
      unsigned int* gp = binBuf + (size_t)b * BINCAP + lbase[b];
      for (int i = t; i < c; i += 256) gp[i] = ebuf[b][i];
    }
  }
}

// ---- phase A2: split each parent bin into 16 sub-bins of 782 dsts ----
// 256 blocks: p = bid&7 (stays on parent's XCD), 32 blocks stride the bin.
// entry2 = (dloc2<<17) | src ; dloc2 = dloc - sub*782 (<782)
__global__ __launch_bounds__(256) void k_bin2(
    const unsigned int* __restrict__ binBuf, const int* __restrict__ gbc,
    unsigned int* __restrict__ binBuf2, int* __restrict__ gbc2) {
  __shared__ unsigned int ebuf[NSUB][LCAP];    // 32 KB
  __shared__ int lcnt[NSUB];
  __shared__ int lbase[NSUB];
  const int t = threadIdx.x;
  const int p = blockIdx.x & 7;
  const int blk = blockIdx.x >> 3;             // 0..31
  const int nb = gbc[p];
  const unsigned int* buf = binBuf + (size_t)p * BINCAP;
  if (t < NSUB) lcnt[t] = 0;
  __syncthreads();
  for (int i0 = blk * 256; i0 < nb; i0 += 32 * 256) {
    int i = i0 + t;
    if (i < nb) {
      unsigned int e = buf[i];
      int dloc = (int)(e >> 17);
      int sub = dloc / SUBW;                   // 0..15
      int p2 = atomicAdd(&lcnt[sub], 1);
      ebuf[sub][p2] = ((unsigned)(dloc - sub * SUBW) << 17) | (e & 131071u);
    }
    __syncthreads();
    if (t < NSUB && lcnt[t] >= 256)
      lbase[t] = atomicAdd(&gbc2[p * NSUB + t], lcnt[t]);
    __syncthreads();
#pragma unroll
    for (int b = 0; b < NSUB; ++b) {
      int c = lcnt[b];
      if (c >= 256) {
        unsigned int* gp = binBuf2 + (size_t)(p * NSUB + b) * SBCAP + lbase[b];
        for (int i2 = t; i2 < c; i2 += 256) gp[i2] = ebuf[b][i2];
      }
    }
    __syncthreads();
    if (t < NSUB && lcnt[t] >= 256) lcnt[t] = 0;
    __syncthreads();
  }
  if (t < NSUB && lcnt[t] > 0)
    lbase[t] = atomicAdd(&gbc2[p * NSUB + t], lcnt[t]);
  __syncthreads();
#pragma unroll
  for (int b = 0; b < NSUB; ++b) {
    int c = lcnt[b];
    if (c > 0) {
      unsigned int* gp = binBuf2 + (size_t)(p * NSUB + b) * SBCAP + lbase[b];
      for (int i2 = t; i2 < c; i2 += 256) gp[i2] = ebuf[b][i2];
    }
  }
}

// ---- phase B: per-sub-bin fill; LDS counters; DENSE csr writes ----
// 128 blocks: p = bid&7, sub = bid>>3. csr slice = 782*32*4 = 100 KB contiguous.
__global__ __launch_bounds__(256) void k_fill4(
    const unsigned int* __restrict__ binBuf2, const int* __restrict__ gbc2,
    int* __restrict__ csr, int* __restrict__ cnt,
    int* __restrict__ ovfc, int* __restrict__ ovf) {
  __shared__ int lcnt[SUBW];
  const int t = threadIdx.x;
  const int p = blockIdx.x & 7;
  const int sub = blockIdx.x >> 3;
  for (int j = t; j < SUBW; j += 256) lcnt[j] = 0;
  __syncthreads();
  const int n2 = gbc2[p * NSUB + sub];
  const unsigned int* buf = binBuf2 + (size_t)(p * NSUB + sub) * SBCAP;
  const int dbase = p * 12500 + sub * SUBW;
  for (int i = t; i < n2; i += 256) {
    unsigned int e = buf[i];
    int dloc2 = (int)(e >> 17);
    int s = (int)(e & 131071u);
    int pos = atomicAdd(&lcnt[dloc2], 1);
    if (pos < PAD) {
      csr[(size_t)(dbase + dloc2) * PAD + pos] = s;
    } else {
      int o = atomicAdd(ovfc, 1);
      ovf[2 * o] = s;
      ovf[2 * o + 1] = dbase + dloc2;
    }
  }
  __syncthreads();
  for (int j = t; j < SUBW; j += 256) {
    int dloc = sub * SUBW + j;
    if (dloc < 12500) {
      int d = p * 12500 + dloc;
      if (d < N_NODES) cnt[d] = lcnt[j] < PAD ? lcnt[j] : PAD;
    }
  }
}

// ---- gather: xa = x + sum_neighbors, bf16 out; csr row = 32 ids (128 B) ----
__global__ __launch_bounds__(256) void k_gather(
    const unsigned short* __restrict__ xh, const int* __restrict__ csr,
    const int* __restrict__ cnt, unsigned short* __restrict__ xa) {
  int wid = (blockIdx.x * 256 + threadIdx.x) >> 6;
  if (wid >= N_NODES) return;
  const int lane = threadIdx.x & 63;
  const int g = lane >> 4;
  const int fl = lane & 15;
  int deg = cnt[wid];
  int myE = csr[(size_t)wid * PAD + (lane & 31)];
  float s0 = 0.f, s1 = 0.f, s2 = 0.f, s3 = 0.f;
  int j = g;
  for (; j + 4 < deg; j += 8) {
    int sA = __shfl(myE, j);
    int sB = __shfl(myE, j + 4);
    ushort4 a = *(const ushort4*)&xh[(size_t)sA * IN_F + fl * 4];
    ushort4 b = *(const ushort4*)&xh[(size_t)sB * IN_F + fl * 4];
    s0 += bf2f(a.x) + bf2f(b.x);
    s1 += bf2f(a.y) + bf2f(b.y);
    s2 += bf2f(a.z) + bf2f(b.z);
    s3 += bf2f(a.w) + bf2f(b.w);
  }
  if (j < deg) {
    int sA = __shfl(myE, j);
    ushort4 a = *(const ushort4*)&xh[(size_t)sA * IN_F + fl * 4];
    s0 += bf2f(a.x); s1 += bf2f(a.y); s2 += bf2f(a.z); s3 += bf2f(a.w);
  }
  s0 += __shfl_xor(s0, 16); s1 += __shfl_xor(s1, 16);
  s2 += __shfl_xor(s2, 16); s3 += __shfl_xor(s3, 16);
  s0 += __shfl_xor(s0, 32); s1 += __shfl_xor(s1, 32);
  s2 += __shfl_xor(s2, 32); s3 += __shfl_xor(s3, 32);
  if (g == 0) {
    ushort4 self = *(const ushort4*)&xh[(size_t)wid * IN_F + fl * 4];
    s0 += bf2f(self.x); s1 += bf2f(self.y);
    s2 += bf2f(self.z); s3 += bf2f(self.w);
    ushort4 r;
    r.x = f2bf(s0); r.y = f2bf(s1); r.z = f2bf(s2); r.w = f2bf(s3);
    *(ushort4*)&xa[(size_t)wid * IN_F + fl * 4] = r;
  }
}

// ---- overflow fixup (deg > PAD; expected ~1 node); lane = feature, race-free ----
__global__ __launch_bounds__(64) void k_ovf2(
    const int* __restrict__ ovf, const int* __restrict__ ovfc,
    const float* __restrict__ x, unsigned short* __restrict__ xa) {
  int n = *ovfc;
  int f = threadIdx.x;
  for (int o = 0; o < n; ++o) {
    int s = ovf[2 * o], d = ovf[2 * o + 1];
    size_t idx = (size_t)d * IN_F + f;
    xa[idx] = f2bf(bf2f(xa[idx]) + x[(size_t)s * IN_F + f]);
  }
}

// ========== MFMA GEMM: LDS-free, 4 waves x 32 rows (2 row-tiles share B) ==========
// C/D layout for mfma_f32_16x16x32_bf16: col = lane&15, row = (lane>>4)*4 + reg.
template <int K, int OUTF32>
__global__ __launch_bounds__(256) void k_mfma(
    const unsigned short* __restrict__ A,
    const unsigned short* __restrict__ Wt,
    const float* __restrict__ bias,
    unsigned short* __restrict__ outh,
    float* __restrict__ outf) {
  const int t = threadIdx.x;
  const int lane = t & 63;
  const int wv = t >> 6;
  const int row16 = lane & 15;
  const int kg = lane >> 4;          // 0..3
  const int NS = K / 32;
  const long r0 = (long)blockIdx.x * 128 + wv * 32;
  long arow0 = r0 + row16;       if (arow0 > N_NODES - 1) arow0 = N_NODES - 1;
  long arow1 = r0 + 16 + row16;  if (arow1 > N_NODES - 1) arow1 = N_NODES - 1;
  bf16x8 a0[K / 32], a1[K / 32];
  {
    const unsigned short* ap0 = A + arow0 * K + kg * 8;
    const unsigned short* ap1 = A + arow1 * K + kg * 8;
#pragma unroll
    for (int s = 0; s < NS; ++s) {
      a0[s] = *(const bf16x8*)(ap0 + s * 32);
      a1[s] = *(const bf16x8*)(ap1 + s * 32);
    }
  }
  f32x4 acc0[8], acc1[8];
#pragma unroll
  for (int n = 0; n < 8; ++n) {
    acc0[n] = (f32x4){0.f, 0.f, 0.f, 0.f};
    acc1[n] = (f32x4){0.f, 0.f, 0.f, 0.f};
  }
  const unsigned short* wp = Wt + (size_t)row16 * K + kg * 8;
#pragma unroll
  for (int n = 0; n < 8; ++n) {
    const unsigned short* wpn = wp + (size_t)n * 16 * K;
    bf16x8 b[K / 32];
#pragma unroll
    for (int s = 0; s < NS; ++s) b[s] = *(const bf16x8*)(wpn + s * 32);
#pragma unroll
    for (int s = 0; s < NS; ++s) {
      acc0[n] = __builtin_amdgcn_mfma_f32_16x16x32_bf16(a0[s], b[s], acc0[n], 0, 0, 0);
      acc1[n] = __builtin_amdgcn_mfma_f32_16x16x32_bf16(a1[s], b[s], acc1[n], 0, 0, 0);
    }
  }
#pragma unroll
  for (int n = 0; n < 8; ++n) {
    int col = n * 16 + row16;
    float bv = bias[col];
#pragma unroll
    for (int r = 0; r < 4; ++r) {
      long row0 = r0 + kg * 4 + r;
      long row1 = r0 + 16 + kg * 4 + r;
      if (row0 < N_NODES) {
        float v = fmaxf(acc0[n][r] + bv, 0.f);
        if (OUTF32) outf[row0 * H_F + col] = v;
        else        outh[row0 * H_F + col] = f2bf(v);
      }
      if (row1 < N_NODES) {
        float v = fmaxf(acc1[n][r] + bv, 0.f);
        if (OUTF32) outf[row1 * H_F + col] = v;
        else        outh[row1 * H_F + col] = f2bf(v);
      }
    }
  }
}

// ---- standalone GraphNorm stats over h3 fp32 (32-row blocks) ----
__global__ __launch_bounds__(256) void k_stats(
    const float* __restrict__ h, const int* __restrict__ batch,
    float* __restrict__ gsum, float* __restrict__ gsumsq) {
  __shared__ __align__(16) float4 sred[256];
  __shared__ __align__(16) float4 qred[256];
  const int t = threadIdx.x;
  const int m0 = blockIdx.x * 32;
  const int tm0 = (t >> 5) * 4, tn0 = (t & 31) * 4;
  const int rg = t >> 5, fq = t & 31;
  float4 v[4];
#pragma unroll
  for (int i = 0; i < 4; ++i)
    v[i] = *(const float4*)&h[(size_t)(m0 + tm0 + i) * H_F + tn0];
  const int glo = batch[m0];
  const int ghi = batch[m0 + 31];
  if (glo == ghi) {
    float4 s = {0,0,0,0}, q = {0,0,0,0};
#pragma unroll
    for (int i = 0; i < 4; ++i) {
      s.x += v[i].x; s.y += v[i].y; s.z += v[i].z; s.w += v[i].w;
      q.x += v[i].x * v[i].x; q.y += v[i].y * v[i].y;
      q.z += v[i].z * v[i].z; q.w += v[i].w * v[i].w;
    }
    sred[rg * 32 + fq] = s;
    qred[rg * 32 + fq] = q;
    __syncthreads();
    if (rg == 0) {
      float4 S = {0,0,0,0}, Q = {0,0,0,0};
#pragma unroll
      for (int j = 0; j < 8; ++j) {
        float4 a0 = sred[j * 32 + fq], b0 = qred[j * 32 + fq];
        S.x += a0.x; S.y += a0.y; S.z += a0.z; S.w += a0.w;
        Q.x += b0.x; Q.y += b0.y; Q.z += b0.z; Q.w += b0.w;
      }
      float* ps = &gsum[(size_t)glo * H_F + fq * 4];
      float* pq = &gsumsq[(size_t)glo * H_F + fq * 4];
      unsafeAtomicAdd(ps + 0, S.x); unsafeAtomicAdd(ps + 1, S.y);
      unsafeAtomicAdd(ps + 2, S.z); unsafeAtomicAdd(ps + 3, S.w);
      unsafeAtomicAdd(pq + 0, Q.x); unsafeAtomicAdd(pq + 1, Q.y);
      unsafeAtomicAdd(pq + 2, Q.z); unsafeAtomicAdd(pq + 3, Q.w);
    }
  } else {
    int gcur = batch[m0 + tm0];
    float4 s = {0,0,0,0}, q = {0,0,0,0};
#pragma unroll
    for (int i = 0; i < 4; ++i) {
      int g = batch[m0 + tm0 + i];
      if (g != gcur) {
        float* ps = &gsum[(size_t)gcur * H_F + tn0];
        float* pq = &gsumsq[(size_t)gcur * H_F + tn0];
        unsafeAtomicAdd(ps + 0, s.x); unsafeAtomicAdd(ps + 1, s.y);
        unsafeAtomicAdd(ps + 2, s.z); unsafeAtomicAdd(ps + 3, s.w);
        unsafeAtomicAdd(pq + 0, q.x); unsafeAtomicAdd(pq + 1, q.y);
        unsafeAtomicAdd(pq + 2, q.z); unsafeAtomicAdd(pq + 3, q.w);
        s = make_float4(0, 0, 0, 0); q = make_float4(0, 0, 0, 0);
        gcur = g;
      }
      s.x += v[i].x; s.y += v[i].y; s.z += v[i].z; s.w += v[i].w;
      q.x += v[i].x * v[i].x; q.y += v[i].y * v[i].y;
      q.z += v[i].z * v[i].z; q.w += v[i].w * v[i].w;
    }
    float* ps = &gsum[(size_t)gcur * H_F + tn0];
    float* pq = &gsumsq[(size_t)gcur * H_F + tn0];
    unsafeAtomicAdd(ps + 0, s.x); unsafeAtomicAdd(ps + 1, s.y);
    unsafeAtomicAdd(ps + 2, s.z); unsafeAtomicAdd(ps + 3, s.w);
    unsafeAtomicAdd(pq + 0, q.x); unsafeAtomicAdd(pq + 1, q.y);
    unsafeAtomicAdd(pq + 2, q.z); unsafeAtomicAdd(pq + 3, q.w);
  }
}

// ---- finalize: per (graph,feature) shift/scale; init flat = -INF ----
__global__ __launch_bounds__(128) void k_finalize(
    const int* __restrict__ batch, const float* __restrict__ gsum,
    const float* __restrict__ gsumsq, const float* __restrict__ gms,
    const float* __restrict__ gw, float* __restrict__ msc,
    float* __restrict__ scale, float* __restrict__ flat) {
  const int g = blockIdx.x;
  const int f = threadIdx.x;
  __shared__ int sb[2];
  if (f < 2) {
    int target = g + f;
    int lo = 0, hi = N_NODES;
    while (lo < hi) { int mid = (lo + hi) >> 1; if (batch[mid] < target) lo = mid + 1; else hi = mid; }
    sb[f] = lo;
  }
  __syncthreads();
  float c = fmaxf((float)(sb[1] - sb[0]), 1.0f);
  float mean = gsum[(size_t)g * H_F + f] / c;
  float ms = mean * gms[f];
  float var = gsumsq[(size_t)g * H_F + f] / c - 2.0f * ms * mean + ms * ms;
  var = fmaxf(var, 0.0f);
  msc[(size_t)g * H_F + f] = ms;
  scale[(size_t)g * H_F + f] = gw[f] * rsqrtf(var + GN_EPS);
  flat[(size_t)g * H_F + f] = -INFINITY;
}

// ---- apply: h = relu((h - msc)*scale + gb); flat = segment max ----
__global__ __launch_bounds__(256) void k_apply(
    float* __restrict__ h, const int* __restrict__ batch,
    const float* __restrict__ msc, const float* __restrict__ scale,
    const float* __restrict__ gb, float* __restrict__ flat) {
  const int t = threadIdx.x;
  const int rg = t >> 5, fq = t & 31;
  const int m0 = blockIdx.x * 32;
  const int r0 = m0 + rg * 4;
  const float4 bb = *(const float4*)&gb[fq * 4];
  const int glo = batch[m0], ghi = batch[m0 + 31];
  __shared__ __align__(16) float4 mred[8][32];
  if (glo == ghi) {
    const float4 m = *(const float4*)&msc[(size_t)glo * H_F + fq * 4];
    const float4 sc = *(const float4*)&scale[(size_t)glo * H_F + fq * 4];
    float4 mx = {-INFINITY, -INFINITY, -INFINITY, -INFINITY};
#pragma unroll
    for (int i = 0; i < 4; ++i) {
      size_t idx = (size_t)(r0 + i) * H_F + fq * 4;
      float4 v = *(const float4*)&h[idx];
      v.x = fmaxf((v.x - m.x) * sc.x + bb.x, 0.f);
      v.y = fmaxf((v.y - m.y) * sc.y + bb.y, 0.f);
      v.z = fmaxf((v.z - m.z) * sc.z + bb.z, 0.f);
      v.w = fmaxf((v.w - m.w) * sc.w + bb.w, 0.f);
      *(float4*)&h[idx] = v;
      mx.x = fmaxf(mx.x, v.x); mx.y = fmaxf(mx.y, v.y);
      mx.z = fmaxf(mx.z, v.z); mx.w = fmaxf(mx.w, v.w);
    }
    mred[rg][fq] = mx;
    __syncthreads();
    if (rg == 0) {
#pragma unroll
      for (int j = 1; j < 8; ++j) {
        float4 a = mred[j][fq];
        mx.x = fmaxf(mx.x, a.x); mx.y = fmaxf(mx.y, a.y);
        mx.z = fmaxf(mx.z, a.z); mx.w = fmaxf(mx.w, a.w);
      }
      int* pf = (int*)&flat[(size_t)glo * H_F + fq * 4];
      atomicMax(pf + 0, __float_as_int(mx.x));
      atomicMax(pf + 1, __float_as_int(mx.y));
      atomicMax(pf + 2, __float_as_int(mx.z));
      atomicMax(pf + 3, __float_as_int(mx.w));
    }
  } else {
    int gcur = batch[r0];
    float4 mm = *(const float4*)&msc[(size_t)gcur * H_F + fq * 4];
    float4 ss = *(const float4*)&scale[(size_t)gcur * H_F + fq * 4];
    float4 mx = {-INFINITY, -INFINITY, -INFINITY, -INFINITY};
#pragma unroll
    for (int i = 0; i < 4; ++i) {
      int g = batch[r0 + i];
      if (g != gcur) {
        int* pf = (int*)&flat[(size_t)gcur * H_F + fq * 4];
        atomicMax(pf + 0, __float_as_int(mx.x));
        atomicMax(pf + 1, __float_as_int(mx.y));
        atomicMax(pf + 2, __float_as_int(mx.z));
        atomicMax(pf + 3, __float_as_int(mx.w));
        mx = make_float4(-INFINITY, -INFINITY, -INFINITY, -INFINITY);
        gcur = g;
        mm = *(const float4*)&msc[(size_t)gcur * H_F + fq * 4];
        ss = *(const float4*)&scale[(size_t)gcur * H_F + fq * 4];
      }
      size_t idx = (size_t)(r0 + i) * H_F + fq * 4;
      float4 v = *(const float4*)&h[idx];
      v.x = fmaxf((v.x - mm.x) * ss.x + bb.x, 0.f);
      v.y = fmaxf((v.y - mm.y) * ss.y + bb.y, 0.f);
      v.z = fmaxf((v.z - mm.z) * ss.z + bb.z, 0.f);
      v.w = fmaxf((v.w - mm.w) * ss.w + bb.w, 0.f);
      *(float4*)&h[idx] = v;
      mx.x = fmaxf(mx.x, v.x); mx.y = fmaxf(mx.y, v.y);
      mx.z = fmaxf(mx.z, v.z); mx.w = fmaxf(mx.w, v.w);
    }
    int* pf = (int*)&flat[(size_t)gcur * H_F + fq * 4];
    atomicMax(pf + 0, __float_as_int(mx.x));
    atomicMax(pf + 1, __float_as_int(mx.y));
    atomicMax(pf + 2, __float_as_int(mx.z));
    atomicMax(pf + 3, __float_as_int(mx.w));
    __syncthreads();
  }
}

// ---------------- passthrough copies ----------------
__global__ __launch_bounds__(256) void k_copy_i2f4(const int4* __restrict__ in,
                                                   float4* __restrict__ out, int n4) {
  int i = blockIdx.x * 256 + threadIdx.x;
  if (i < n4) {
    int4 v = in[i];
    out[i] = make_float4((float)v.x, (float)v.y, (float)v.z, (float)v.w);
  }
}
__global__ __launch_bounds__(256) void k_copy_f4(const float4* __restrict__ in,
                                                 float4* __restrict__ out, int n4) {
  int i = blockIdx.x * 256 + threadIdx.x;
  if (i < n4) out[i] = in[i];
}

extern "C" void kernel_launch(void* const* d_in, const int* in_sizes, int n_in,
                              void* d_out, int out_size, void* d_ws, size_t ws_size,
                              hipStream_t stream) {
  const float* inputs = (const float*)d_in[0];
  const int*   ei     = (const int*)d_in[1];
  const int*   batch  = (const int*)d_in[2];
  const float* eattr  = (const float*)d_in[3];
  const float* W1 = (const float*)d_in[4];
  const float* b1 = (const float*)d_in[5];
  const float* W2 = (const float*)d_in[6];
  const float* b2 = (const float*)d_in[7];
  const float* W3 = (const float*)d_in[8];
  const float* b3 = (const float*)d_in[9];
  const float* gw  = (const float*)d_in[10];
  const float* gb  = (const float*)d_in[11];
  const float* gms = (const float*)d_in[12];

  float* out = (float*)d_out;
  float* hemb  = out;                          // [100000,128] fp32
  float* flat  = out + 12800000;               // [256,128]
  float* o_ei  = out + 12832768;               // [2,1600000]
  float* o_ea  = out + 16032768;               // [1600000,8]
  float* o_b   = out + 28832768;               // [100000]

  // Scratch (all dead before their region is finally written):
  //  hemb region (51.2MB): binBuf u32 8MB @0, binBuf2 u32 8MB @2M floats,
  //                        xh bf16 @4.2M floats, xa bf16 @7.6M floats
  //  o_ea region: csr [100000][32] ints @0 (12.8MB) -> h2 bf16 after gather;
  //               h1 bf16 @6.4M floats
  //  o_ei region: cnt/ovfc/gbc/gbc2/ovf + gsum/gsumq/msc/scl + Wt bf16
  unsigned int*   binBuf  = (unsigned int*)hemb;
  unsigned int*   binBuf2 = (unsigned int*)(hemb + 2000000);
  unsigned short* xh = (unsigned short*)(hemb + 4200000);
  unsigned short* xa = (unsigned short*)(hemb + 7600000);
  int*            csr = (int*)o_ea;
  unsigned short* h2  = (unsigned short*)o_ea;
  unsigned short* h1  = (unsigned short*)(o_ea + 6400000);
  int*   cnt   = (int*)o_ei;                    // [N_NODES] (fully written by k_fill4)
  int*   ovfc  = (int*)o_ei + 100000;           // [1]
  int*   gbc   = (int*)o_ei + 100008;           // [8]
  int*   gbc2  = (int*)o_ei + 100016;           // [128]
  int*   ovf   = (int*)o_ei + 100160;           // pairs, tiny
  float* gsum  = o_ei + 200000;
  float* gsumq = o_ei + 232768;
  float* msc   = o_ei + 265536;
  float* scl   = o_ei + 298304;
  unsigned short* wt  = (unsigned short*)(o_ei + 350000);
  unsigned short* wt1 = wt;
  unsigned short* wt2 = wt + 8192;
  unsigned short* wt3 = wt + 24576;

  hipMemsetAsync(ovfc, 0, 160 * sizeof(int), stream);   // ovfc + gbc + gbc2
  hipMemsetAsync(gsum, 0, 2 * N_GRAPHS * H_F * sizeof(float), stream);
  k_prepW<<<160, 256, 0, stream>>>(W1, W2, W3, wt);
  k_cast<<<(N_NODES * IN_F / 4 + 255) / 256, 256, 0, stream>>>(
      (const float4*)inputs, (ushort4*)xh, N_NODES * IN_F / 4);
  k_bin<<<512, 256, 0, stream>>>(ei, ei + N_EDGES, binBuf, gbc);
  k_bin2<<<256, 256, 0, stream>>>(binBuf, gbc, binBuf2, gbc2);
  k_fill4<<<NBINS * NSUB, 256, 0, stream>>>(binBuf2, gbc2, csr, cnt, ovfc, ovf);
  k_gather<<<(N_NODES * 64 + 255) / 256, 256, 0, stream>>>(xh, csr, cnt, xa);
  k_ovf2<<<1, 64, 0, stream>>>(ovf, ovfc, inputs, xa);
  const int mg = (N_NODES + 127) / 128;   // 782
  k_mfma<64, 0><<<mg, 256, 0, stream>>>(xa, wt1, b1, h1, nullptr);
  k_mfma<128, 0><<<mg, 256, 0, stream>>>(h1, wt2, b2, h2, nullptr);
  k_mfma<128, 1><<<mg, 256, 0, stream>>>(h2, wt3, b3, nullptr, hemb);
  k_stats<<<N_NODES / 32, 256, 0, stream>>>(hemb, batch, gsum, gsumq);
  k_finalize<<<N_GRAPHS, 128, 0, stream>>>(batch, gsum, gsumq, gms, gw, msc, scl, flat);
  k_apply<<<N_NODES / 32, 256, 0, stream>>>(hemb, batch, msc, scl, gb, flat);
  k_copy_i2f4<<<(2 * N_EDGES / 4 + 255) / 256, 256, 0, stream>>>((const int4*)ei, (float4*)o_ei, 2 * N_EDGES / 4);
  k_copy_f4<<<(N_EDGES * 2 + 255) / 256, 256, 0, stream>>>((const float4*)eattr, (float4*)o_ea, N_EDGES * 2);
  k_copy_i2f4<<<(N_NODES / 4 + 255) / 256, 256, 0, stream>>>((const int4*)batch, (float4*)o_b, N_NODES / 4);
}

// Round 13
// 328.651 us; speedup vs baseline: 1.5997x; 1.0142x over previous
//
#include <hip/hip_runtime.h>
#include <math.h>

#define N_NODES 100000
#define N_EDGES 1600000
#define N_GRAPHS 256
#define IN_F 64
#define H_F 128
#define GN_EPS 1e-5f
#define PAD 32
#define NBINS 8
#define LCAP 512
#define BINCAP (1 << 18)
#define NSUB 16
#define SUBW 782            // 16*782 = 12512 >= 12500
#define SBCAP 16384         // entries per sub-bin (expected ~12.5K)

typedef __attribute__((ext_vector_type(8))) short bf16x8;
typedef __attribute__((ext_vector_type(4))) float f32x4;

__device__ __forceinline__ float bf2f(unsigned short u) {
  return __uint_as_float(((unsigned int)u) << 16);
}
__device__ __forceinline__ unsigned short f2bf(float f) {
  unsigned int u = __float_as_uint(f);
  u += 0x7FFFu + ((u >> 16) & 1u);
  return (unsigned short)(u >> 16);
}

// ---- cast x to bf16 (RTNE) ----
__global__ __launch_bounds__(256) void k_cast(const float4* __restrict__ in,
                                              ushort4* __restrict__ out, int n4) {
  int i = blockIdx.x * 256 + threadIdx.x;
  if (i < n4) {
    float4 v = in[i];
    ushort4 o;
    o.x = f2bf(v.x); o.y = f2bf(v.y); o.z = f2bf(v.z); o.w = f2bf(v.w);
    out[i] = o;
  }
}

// ---- pre-transpose weights to bf16 Wt[n][k] ----
__global__ __launch_bounds__(256) void k_prepW(
    const float* __restrict__ W1, const float* __restrict__ W2,
    const float* __restrict__ W3, unsigned short* __restrict__ wt) {
  int i = blockIdx.x * 256 + threadIdx.x;
  if (i < 8192) {                            // Wt1 [128][64]
    int n = i >> 6, k = i & 63;
    wt[i] = f2bf(W1[(size_t)k * H_F + n]);
  } else if (i < 24576) {                    // Wt2 [128][128]
    int j = i - 8192;
    int n = j >> 7, k = j & 127;
    wt[i] = f2bf(W2[(size_t)k * H_F + n]);
  } else if (i < 40960) {                    // Wt3 [128][128]
    int j = i - 24576;
    int n = j >> 7, k = j & 127;
    wt[i] = f2bf(W3[(size_t)k * H_F + n]);
  }
}

// ---- phase A: radix partition edges into 8 dst-range bins; u32-packed ----
// entry = (dloc<<17) | src ; dloc = d - p*12500 (<2^14), src < 2^17
__global__ __launch_bounds__(256) void k_bin(
    const int* __restrict__ src, const int* __restrict__ dst,
    unsigned int* __restrict__ binBuf, int* __restrict__ gbc) {
  __shared__ unsigned int ebuf[NBINS][LCAP];   // 16 KB
  __shared__ int lcnt[NBINS];
  __shared__ int lbase[NBINS];
  const int t = threadIdx.x;
  if (t < NBINS) lcnt[t] = 0;
  __syncthreads();
  for (int e0 = blockIdx.x * 256; e0 < N_EDGES; e0 += gridDim.x * 256) {
    int e = e0 + t;
    if (e < N_EDGES) {
      int s = src[e], d = dst[e];
      int b = d / 12500;
      int p = atomicAdd(&lcnt[b], 1);
      ebuf[b][p] = ((unsigned)(d - b * 12500) << 17) | (unsigned)s;
    }
    __syncthreads();
    if (t < NBINS && lcnt[t] >= 256) lbase[t] = atomicAdd(&gbc[t], lcnt[t]);
    __syncthreads();
#pragma unroll
    for (int b = 0; b < NBINS; ++b) {
      int c = lcnt[b];
      if (c >= 256) {
        unsigned int* gp = binBuf + (size_t)b * BINCAP + lbase[b];
        for (int i = t; i < c; i += 256) gp[i] = ebuf[b][i];
      }
    }
    __syncthreads();
    if (t < NBINS && lcnt[t] >= 256) lcnt[t] = 0;
    __syncthreads();
  }
  if (t < NBINS && lcnt[t] > 0) lbase[t] = atomicAdd(&gbc[t], lcnt[t]);
  __syncthreads();
#pragma unroll
  for (int b = 0; b < NBINS; ++b) {
    int c = lcnt[b];
    if (c > 0) {
      unsigned int* gp = binBuf + (size_t)b * BINCAP + lbase[b];
      for (int i = t; i < c; i += 256) gp[i] = ebuf[b][i];
    }
  }
}

// ---- phase A2: split each parent bin into 16 sub-bins of 782 dsts ----
// 256 blocks: p = bid&7 (stays on parent's XCD), 32 blocks stride the bin.
// entry2 = (dloc2<<17) | src ; dloc2 = dloc - sub*782 (<782)
__global__ __launch_bounds__(256) void k_bin2(
    const unsigned int* __restrict__ binBuf, const int* __restrict__ gbc,
    unsigned int* __restrict__ binBuf2, int* __restrict__ gbc2) {
  __shared__ unsigned int ebuf[NSUB][LCAP];    // 32 KB
  __shared__ int lcnt[NSUB];
  __shared__ int lbase[NSUB];
  const int t = threadIdx.x;
  const int p = blockIdx.x & 7;
  const int blk = blockIdx.x >> 3;             // 0..31
  const int nb = gbc[p];
  const unsigned int* buf = binBuf + (size_t)p * BINCAP;
  if (t < NSUB) lcnt[t] = 0;
  __syncthreads();
  for (int i0 = blk * 256; i0 < nb; i0 += 32 * 256) {
    int i = i0 + t;
    if (i < nb) {
      unsigned int e = buf[i];
      int dloc = (int)(e >> 17);
      int sub = dloc / SUBW;                   // 0..15
      int p2 = atomicAdd(&lcnt[sub], 1);
      ebuf[sub][p2] = ((unsigned)(dloc - sub * SUBW) << 17) | (e & 131071u);
    }
    __syncthreads();
    if (t < NSUB && lcnt[t] >= 256)
      lbase[t] = atomicAdd(&gbc2[p * NSUB + t], lcnt[t]);
    __syncthreads();
#pragma unroll
    for (int b = 0; b < NSUB; ++b) {
      int c = lcnt[b];
      if (c >= 256) {
        unsigned int* gp = binBuf2 + (size_t)(p * NSUB + b) * SBCAP + lbase[b];
        for (int i2 = t; i2 < c; i2 += 256) gp[i2] = ebuf[b][i2];
      }
    }
    __syncthreads();
    if (t < NSUB && lcnt[t] >= 256) lcnt[t] = 0;
    __syncthreads();
  }
  if (t < NSUB && lcnt[t] > 0)
    lbase[t] = atomicAdd(&gbc2[p * NSUB + t], lcnt[t]);
  __syncthreads();
#pragma unroll
  for (int b = 0; b < NSUB; ++b) {
    int c = lcnt[b];
    if (c > 0) {
      unsigned int* gp = binBuf2 + (size_t)(p * NSUB + b) * SBCAP + lbase[b];
      for (int i2 = t; i2 < c; i2 += 256) gp[i2] = ebuf[b][i2];
    }
  }
}

// ---- phase B: per-sub-bin fill; csr slice ASSEMBLED IN LDS, dense copy-out ----
// 128 blocks: p = bid&7, sub = bid>>3. LDS: lcsr 100KB + lcnt 3KB.
// No scattered global stores anywhere -> full-line write-back only.
__global__ __launch_bounds__(256) void k_fill5(
    const unsigned int* __restrict__ binBuf2, const int* __restrict__ gbc2,
    int* __restrict__ csr, int* __restrict__ cnt,
    int* __restrict__ ovfc, int* __restrict__ ovf) {
  __shared__ int lcsr[SUBW * PAD];   // 100,096 B
  __shared__ int lcnt[SUBW];
  const int t = threadIdx.x;
  const int p = blockIdx.x & 7;
  const int sub = blockIdx.x >> 3;
  for (int j = t; j < SUBW; j += 256) lcnt[j] = 0;
  __syncthreads();
  const int n2 = gbc2[p * NSUB + sub];
  const unsigned int* buf = binBuf2 + (size_t)(p * NSUB + sub) * SBCAP;
  const int dbase = p * 12500 + sub * SUBW;
  for (int i = t; i < n2; i += 256) {
    unsigned int e = buf[i];
    int dloc2 = (int)(e >> 17);
    int s = (int)(e & 131071u);
    int pos = atomicAdd(&lcnt[dloc2], 1);
    if (pos < PAD) {
      lcsr[dloc2 * PAD + pos] = s;
    } else {
      int o = atomicAdd(ovfc, 1);
      ovf[2 * o] = s;
      ovf[2 * o + 1] = dbase + dloc2;
    }
  }
  __syncthreads();
  int rows = 12500 - sub * SUBW; if (rows > SUBW) rows = SUBW;
  int total4 = rows * (PAD / 4);
  int4* dst4 = (int4*)(csr + (size_t)dbase * PAD);
  const int4* src4 = (const int4*)lcsr;
  for (int i = t; i < total4; i += 256) dst4[i] = src4[i];
  for (int j = t; j < rows; j += 256)
    cnt[dbase + j] = lcnt[j] < PAD ? lcnt[j] : PAD;
}

// ---- gather: xa = x + sum_neighbors, bf16 out; csr row = 32 ids (128 B) ----
__global__ __launch_bounds__(256) void k_gather(
    const unsigned short* __restrict__ xh, const int* __restrict__ csr,
    const int* __restrict__ cnt, unsigned short* __restrict__ xa) {
  int wid = (blockIdx.x * 256 + threadIdx.x) >> 6;
  if (wid >= N_NODES) return;
  const int lane = threadIdx.x & 63;
  const int g = lane >> 4;
  const int fl = lane & 15;
  int deg = cnt[wid];
  int myE = csr[(size_t)wid * PAD + (lane & 31)];
  float s0 = 0.f, s1 = 0.f, s2 = 0.f, s3 = 0.f;
  int j = g;
  for (; j + 4 < deg; j += 8) {
    int sA = __shfl(myE, j);
    int sB = __shfl(myE, j + 4);
    ushort4 a = *(const ushort4*)&xh[(size_t)sA * IN_F + fl * 4];
    ushort4 b = *(const ushort4*)&xh[(size_t)sB * IN_F + fl * 4];
    s0 += bf2f(a.x) + bf2f(b.x);
    s1 += bf2f(a.y) + bf2f(b.y);
    s2 += bf2f(a.z) + bf2f(b.z);
    s3 += bf2f(a.w) + bf2f(b.w);
  }
  if (j < deg) {
    int sA = __shfl(myE, j);
    ushort4 a = *(const ushort4*)&xh[(size_t)sA * IN_F + fl * 4];
    s0 += bf2f(a.x); s1 += bf2f(a.y); s2 += bf2f(a.z); s3 += bf2f(a.w);
  }
  s0 += __shfl_xor(s0, 16); s1 += __shfl_xor(s1, 16);
  s2 += __shfl_xor(s2, 16); s3 += __shfl_xor(s3, 16);
  s0 += __shfl_xor(s0, 32); s1 += __shfl_xor(s1, 32);
  s2 += __shfl_xor(s2, 32); s3 += __shfl_xor(s3, 32);
  if (g == 0) {
    ushort4 self = *(const ushort4*)&xh[(size_t)wid * IN_F + fl * 4];
    s0 += bf2f(self.x); s1 += bf2f(self.y);
    s2 += bf2f(self.z); s3 += bf2f(self.w);
    ushort4 r;
    r.x = f2bf(s0); r.y = f2bf(s1); r.z = f2bf(s2); r.w = f2bf(s3);
    *(ushort4*)&xa[(size_t)wid * IN_F + fl * 4] = r;
  }
}

// ---- overflow fixup (deg > PAD; expected ~1 node); lane = feature, race-free ----
__global__ __launch_bounds__(64) void k_ovf2(
    const int* __restrict__ ovf, const int* __restrict__ ovfc,
    const float* __restrict__ x, unsigned short* __restrict__ xa) {
  int n = *ovfc;
  int f = threadIdx.x;
  for (int o = 0; o < n; ++o) {
    int s = ovf[2 * o], d = ovf[2 * o + 1];
    size_t idx = (size_t)d * IN_F + f;
    xa[idx] = f2bf(bf2f(xa[idx]) + x[(size_t)s * IN_F + f]);
  }
}

// ========== MFMA GEMM: LDS-free, 4 waves x 32 rows (2 row-tiles share B) ==========
// C/D layout for mfma_f32_16x16x32_bf16: col = lane&15, row = (lane>>4)*4 + reg.
template <int K, int OUTF32>
__global__ __launch_bounds__(256) void k_mfma(
    const unsigned short* __restrict__ A,
    const unsigned short* __restrict__ Wt,
    const float* __restrict__ bias,
    unsigned short* __restrict__ outh,
    float* __restrict__ outf) {
  const int t = threadIdx.x;
  const int lane = t & 63;
  const int wv = t >> 6;
  const int row16 = lane & 15;
  const int kg = lane >> 4;          // 0..3
  const int NS = K / 32;
  const long r0 = (long)blockIdx.x * 128 + wv * 32;
  long arow0 = r0 + row16;       if (arow0 > N_NODES - 1) arow0 = N_NODES - 1;
  long arow1 = r0 + 16 + row16;  if (arow1 > N_NODES - 1) arow1 = N_NODES - 1;
  bf16x8 a0[K / 32], a1[K / 32];
  {
    const unsigned short* ap0 = A + arow0 * K + kg * 8;
    const unsigned short* ap1 = A + arow1 * K + kg * 8;
#pragma unroll
    for (int s = 0; s < NS; ++s) {
      a0[s] = *(const bf16x8*)(ap0 + s * 32);
      a1[s] = *(const bf16x8*)(ap1 + s * 32);
    }
  }
  f32x4 acc0[8], acc1[8];
#pragma unroll
  for (int n = 0; n < 8; ++n) {
    acc0[n] = (f32x4){0.f, 0.f, 0.f, 0.f};
    acc1[n] = (f32x4){0.f, 0.f, 0.f, 0.f};
  }
  const unsigned short* wp = Wt + (size_t)row16 * K + kg * 8;
#pragma unroll
  for (int n = 0; n < 8; ++n) {
    const unsigned short* wpn = wp + (size_t)n * 16 * K;
    bf16x8 b[K / 32];
#pragma unroll
    for (int s = 0; s < NS; ++s) b[s] = *(const bf16x8*)(wpn + s * 32);
#pragma unroll
    for (int s = 0; s < NS; ++s) {
      acc0[n] = __builtin_amdgcn_mfma_f32_16x16x32_bf16(a0[s], b[s], acc0[n], 0, 0, 0);
      acc1[n] = __builtin_amdgcn_mfma_f32_16x16x32_bf16(a1[s], b[s], acc1[n], 0, 0, 0);
    }
  }
#pragma unroll
  for (int n = 0; n < 8; ++n) {
    int col = n * 16 + row16;
    float bv = bias[col];
#pragma unroll
    for (int r = 0; r < 4; ++r) {
      long row0 = r0 + kg * 4 + r;
      long row1 = r0 + 16 + kg * 4 + r;
      if (row0 < N_NODES) {
        float v = fmaxf(acc0[n][r] + bv, 0.f);
        if (OUTF32) outf[row0 * H_F + col] = v;
        else        outh[row0 * H_F + col] = f2bf(v);
      }
      if (row1 < N_NODES) {
        float v = fmaxf(acc1[n][r] + bv, 0.f);
        if (OUTF32) outf[row1 * H_F + col] = v;
        else        outh[row1 * H_F + col] = f2bf(v);
      }
    }
  }
}

// ---- standalone GraphNorm stats over h3 fp32 (32-row blocks) ----
__global__ __launch_bounds__(256) void k_stats(
    const float* __restrict__ h, const int* __restrict__ batch,
    float* __restrict__ gsum, float* __restrict__ gsumsq) {
  __shared__ __align__(16) float4 sred[256];
  __shared__ __align__(16) float4 qred[256];
  const int t = threadIdx.x;
  const int m0 = blockIdx.x * 32;
  const int tm0 = (t >> 5) * 4, tn0 = (t & 31) * 4;
  const int rg = t >> 5, fq = t & 31;
  float4 v[4];
#pragma unroll
  for (int i = 0; i < 4; ++i)
    v[i] = *(const float4*)&h[(size_t)(m0 + tm0 + i) * H_F + tn0];
  const int glo = batch[m0];
  const int ghi = batch[m0 + 31];
  if (glo == ghi) {
    float4 s = {0,0,0,0}, q = {0,0,0,0};
#pragma unroll
    for (int i = 0; i < 4; ++i) {
      s.x += v[i].x; s.y += v[i].y; s.z += v[i].z; s.w += v[i].w;
      q.x += v[i].x * v[i].x; q.y += v[i].y * v[i].y;
      q.z += v[i].z * v[i].z; q.w += v[i].w * v[i].w;
    }
    sred[rg * 32 + fq] = s;
    qred[rg * 32 + fq] = q;
    __syncthreads();
    if (rg == 0) {
      float4 S = {0,0,0,0}, Q = {0,0,0,0};
#pragma unroll
      for (int j = 0; j < 8; ++j) {
        float4 a0 = sred[j * 32 + fq], b0 = qred[j * 32 + fq];
        S.x += a0.x; S.y += a0.y; S.z += a0.z; S.w += a0.w;
        Q.x += b0.x; Q.y += b0.y; Q.z += b0.z; Q.w += b0.w;
      }
      float* ps = &gsum[(size_t)glo * H_F + fq * 4];
      float* pq = &gsumsq[(size_t)glo * H_F + fq * 4];
      unsafeAtomicAdd(ps + 0, S.x); unsafeAtomicAdd(ps + 1, S.y);
      unsafeAtomicAdd(ps + 2, S.z); unsafeAtomicAdd(ps + 3, S.w);
      unsafeAtomicAdd(pq + 0, Q.x); unsafeAtomicAdd(pq + 1, Q.y);
      unsafeAtomicAdd(pq + 2, Q.z); unsafeAtomicAdd(pq + 3, Q.w);
    }
  } else {
    int gcur = batch[m0 + tm0];
    float4 s = {0,0,0,0}, q = {0,0,0,0};
#pragma unroll
    for (int i = 0; i < 4; ++i) {
      int g = batch[m0 + tm0 + i];
      if (g != gcur) {
        float* ps = &gsum[(size_t)gcur * H_F + tn0];
        float* pq = &gsumsq[(size_t)gcur * H_F + tn0];
        unsafeAtomicAdd(ps + 0, s.x); unsafeAtomicAdd(ps + 1, s.y);
        unsafeAtomicAdd(ps + 2, s.z); unsafeAtomicAdd(ps + 3, s.w);
        unsafeAtomicAdd(pq + 0, q.x); unsafeAtomicAdd(pq + 1, q.y);
        unsafeAtomicAdd(pq + 2, q.z); unsafeAtomicAdd(pq + 3, q.w);
        s = make_float4(0, 0, 0, 0); q = make_float4(0, 0, 0, 0);
        gcur = g;
      }
      s.x += v[i].x; s.y += v[i].y; s.z += v[i].z; s.w += v[i].w;
      q.x += v[i].x * v[i].x; q.y += v[i].y * v[i].y;
      q.z += v[i].z * v[i].z; q.w += v[i].w * v[i].w;
    }
    float* ps = &gsum[(size_t)gcur * H_F + tn0];
    float* pq = &gsumsq[(size_t)gcur * H_F + tn0];
    unsafeAtomicAdd(ps + 0, s.x); unsafeAtomicAdd(ps + 1, s.y);
    unsafeAtomicAdd(ps + 2, s.z); unsafeAtomicAdd(ps + 3, s.w);
    unsafeAtomicAdd(pq + 0, q.x); unsafeAtomicAdd(pq + 1, q.y);
    unsafeAtomicAdd(pq + 2, q.z); unsafeAtomicAdd(pq + 3, q.w);
  }
}

// ---- finalize: per (graph,feature) shift/scale; init flat = -INF ----
__global__ __launch_bounds__(128) void k_finalize(
    const int* __restrict__ batch, const float* __restrict__ gsum,
    const float* __restrict__ gsumsq, const float* __restrict__ gms,
    const float* __restrict__ gw, float* __restrict__ msc,
    float* __restrict__ scale, float* __restrict__ flat) {
  const int g = blockIdx.x;
  const int f = threadIdx.x;
  __shared__ int sb[2];
  if (f < 2) {
    int target = g + f;
    int lo = 0, hi = N_NODES;
    while (lo < hi) { int mid = (lo + hi) >> 1; if (batch[mid] < target) lo = mid + 1; else hi = mid; }
    sb[f] = lo;
  }
  __syncthreads();
  float c = fmaxf((float)(sb[1] - sb[0]), 1.0f);
  float mean = gsum[(size_t)g * H_F + f] / c;
  float ms = mean * gms[f];
  float var = gsumsq[(size_t)g * H_F + f] / c - 2.0f * ms * mean + ms * ms;
  var = fmaxf(var, 0.0f);
  msc[(size_t)g * H_F + f] = ms;
  scale[(size_t)g * H_F + f] = gw[f] * rsqrtf(var + GN_EPS);
  flat[(size_t)g * H_F + f] = -INFINITY;
}

// ---- apply: h = relu((h - msc)*scale + gb); flat = segment max ----
__global__ __launch_bounds__(256) void k_apply(
    float* __restrict__ h, const int* __restrict__ batch,
    const float* __restrict__ msc, const float* __restrict__ scale,
    const float* __restrict__ gb, float* __restrict__ flat) {
  const int t = threadIdx.x;
  const int rg = t >> 5, fq = t & 31;
  const int m0 = blockIdx.x * 32;
  const int r0 = m0 + rg * 4;
  const float4 bb = *(const float4*)&gb[fq * 4];
  const int glo = batch[m0], ghi = batch[m0 + 31];
  __shared__ __align__(16) float4 mred[8][32];
  if (glo == ghi) {
    const float4 m = *(const float4*)&msc[(size_t)glo * H_F + fq * 4];
    const float4 sc = *(const float4*)&scale[(size_t)glo * H_F + fq * 4];
    float4 mx = {-INFINITY, -INFINITY, -INFINITY, -INFINITY};
#pragma unroll
    for (int i = 0; i < 4; ++i) {
      size_t idx = (size_t)(r0 + i) * H_F + fq * 4;
      float4 v = *(const float4*)&h[idx];
      v.x = fmaxf((v.x - m.x) * sc.x + bb.x, 0.f);
      v.y = fmaxf((v.y - m.y) * sc.y + bb.y, 0.f);
      v.z = fmaxf((v.z - m.z) * sc.z + bb.z, 0.f);
      v.w = fmaxf((v.w - m.w) * sc.w + bb.w, 0.f);
      *(float4*)&h[idx] = v;
      mx.x = fmaxf(mx.x, v.x); mx.y = fmaxf(mx.y, v.y);
      mx.z = fmaxf(mx.z, v.z); mx.w = fmaxf(mx.w, v.w);
    }
    mred[rg][fq] = mx;
    __syncthreads();
    if (rg == 0) {
#pragma unroll
      for (int j = 1; j < 8; ++j) {
        float4 a = mred[j][fq];
        mx.x = fmaxf(mx.x, a.x); mx.y = fmaxf(mx.y, a.y);
        mx.z = fmaxf(mx.z, a.z); mx.w = fmaxf(mx.w, a.w);
      }
      int* pf = (int*)&flat[(size_t)glo * H_F + fq * 4];
      atomicMax(pf + 0, __float_as_int(mx.x));
      atomicMax(pf + 1, __float_as_int(mx.y));
      atomicMax(pf + 2, __float_as_int(mx.z));
      atomicMax(pf + 3, __float_as_int(mx.w));
    }
  } else {
    int gcur = batch[r0];
    float4 mm = *(const float4*)&msc[(size_t)gcur * H_F + fq * 4];
    float4 ss = *(const float4*)&scale[(size_t)gcur * H_F + fq * 4];
    float4 mx = {-INFINITY, -INFINITY, -INFINITY, -INFINITY};
#pragma unroll
    for (int i = 0; i < 4; ++i) {
      int g = batch[r0 + i];
      if (g != gcur) {
        int* pf = (int*)&flat[(size_t)gcur * H_F + fq * 4];
        atomicMax(pf + 0, __float_as_int(mx.x));
        atomicMax(pf + 1, __float_as_int(mx.y));
        atomicMax(pf + 2, __float_as_int(mx.z));
        atomicMax(pf + 3, __float_as_int(mx.w));
        mx = make_float4(-INFINITY, -INFINITY, -INFINITY, -INFINITY);
        gcur = g;
        mm = *(const float4*)&msc[(size_t)gcur * H_F + fq * 4];
        ss = *(const float4*)&scale[(size_t)gcur * H_F + fq * 4];
      }
      size_t idx = (size_t)(r0 + i) * H_F + fq * 4;
      float4 v = *(const float4*)&h[idx];
      v.x = fmaxf((v.x - mm.x) * ss.x + bb.x, 0.f);
      v.y = fmaxf((v.y - mm.y) * ss.y + bb.y, 0.f);
      v.z = fmaxf((v.z - mm.z) * ss.z + bb.z, 0.f);
      v.w = fmaxf((v.w - mm.w) * ss.w + bb.w, 0.f);
      *(float4*)&h[idx] = v;
      mx.x = fmaxf(mx.x, v.x); mx.y = fmaxf(mx.y, v.y);
      mx.z = fmaxf(mx.z, v.z); mx.w = fmaxf(mx.w, v.w);
    }
    int* pf = (int*)&flat[(size_t)gcur * H_F + fq * 4];
    atomicMax(pf + 0, __float_as_int(mx.x));
    atomicMax(pf + 1, __float_as_int(mx.y));
    atomicMax(pf + 2, __float_as_int(mx.z));
    atomicMax(pf + 3, __float_as_int(mx.w));
    __syncthreads();
  }
}

// ---------------- passthrough copies ----------------
__global__ __launch_bounds__(256) void k_copy_i2f4(const int4* __restrict__ in,
                                                   float4* __restrict__ out, int n4) {
  int i = blockIdx.x * 256 + threadIdx.x;
  if (i < n4) {
    int4 v = in[i];
    out[i] = make_float4((float)v.x, (float)v.y, (float)v.z, (float)v.w);
  }
}
__global__ __launch_bounds__(256) void k_copy_f4(const float4* __restrict__ in,
                                                 float4* __restrict__ out, int n4) {
  int i = blockIdx.x * 256 + threadIdx.x;
  if (i < n4) out[i] = in[i];
}

extern "C" void kernel_launch(void* const* d_in, const int* in_sizes, int n_in,
                              void* d_out, int out_size, void* d_ws, size_t ws_size,
                              hipStream_t stream) {
  const float* inputs = (const float*)d_in[0];
  const int*   ei     = (const int*)d_in[1];
  const int*   batch  = (const int*)d_in[2];
  const float* eattr  = (const float*)d_in[3];
  const float* W1 = (const float*)d_in[4];
  const float* b1 = (const float*)d_in[5];
  const float* W2 = (const float*)d_in[6];
  const float* b2 = (const float*)d_in[7];
  const float* W3 = (const float*)d_in[8];
  const float* b3 = (const float*)d_in[9];
  const float* gw  = (const float*)d_in[10];
  const float* gb  = (const float*)d_in[11];
  const float* gms = (const float*)d_in[12];

  float* out = (float*)d_out;
  float* hemb  = out;                          // [100000,128] fp32
  float* flat  = out + 12800000;               // [256,128]
  float* o_ei  = out + 12832768;               // [2,1600000]
  float* o_ea  = out + 16032768;               // [1600000,8]
  float* o_b   = out + 28832768;               // [100000]

  // Scratch (all dead before their region is finally written):
  //  hemb region (51.2MB): binBuf u32 [0, 2,097,152), binBuf2 u32 @2,100,000
  //                        (2.1M span, no overlap), xh bf16 @4.2M floats,
  //                        xa bf16 @7.6M floats
  //  o_ea region: csr [100000][32] ints @0 (12.8MB) -> h2 bf16 after gather;
  //               h1 bf16 @6.4M floats
  //  o_ei region: cnt/ovfc/gbc/gbc2/ovf + gsum/gsumq/msc/scl + Wt bf16
  unsigned int*   binBuf  = (unsigned int*)hemb;
  unsigned int*   binBuf2 = (unsigned int*)(hemb + 2100000);
  unsigned short* xh = (unsigned short*)(hemb + 4200000);
  unsigned short* xa = (unsigned short*)(hemb + 7600000);
  int*            csr = (int*)o_ea;
  unsigned short* h2  = (unsigned short*)o_ea;
  unsigned short* h1  = (unsigned short*)(o_ea + 6400000);
  int*   cnt   = (int*)o_ei;                    // [N_NODES] (fully written by k_fill5)
  int*   ovfc  = (int*)o_ei + 100000;           // [1]
  int*   gbc   = (int*)o_ei + 100008;           // [8]
  int*   gbc2  = (int*)o_ei + 100016;           // [128]
  int*   ovf   = (int*)o_ei + 100160;           // pairs, tiny
  float* gsum  = o_ei + 200000;
  float* gsumq = o_ei + 232768;
  float* msc   = o_ei + 265536;
  float* scl   = o_ei + 298304;
  unsigned short* wt  = (unsigned short*)(o_ei + 350000);
  unsigned short* wt1 = wt;
  unsigned short* wt2 = wt + 8192;
  unsigned short* wt3 = wt + 24576;

  hipMemsetAsync(ovfc, 0, 160 * sizeof(int), stream);   // ovfc + gbc + gbc2
  hipMemsetAsync(gsum, 0, 2 * N_GRAPHS * H_F * sizeof(float), stream);
  k_prepW<<<160, 256, 0, stream>>>(W1, W2, W3, wt);
  k_cast<<<(N_NODES * IN_F / 4 + 255) / 256, 256, 0, stream>>>(
      (const float4*)inputs, (ushort4*)xh, N_NODES * IN_F / 4);
  k_bin<<<512, 256, 0, stream>>>(ei, ei + N_EDGES, binBuf, gbc);
  k_bin2<<<256, 256, 0, stream>>>(binBuf, gbc, binBuf2, gbc2);
  k_fill5<<<NBINS * NSUB, 256, 0, stream>>>(binBuf2, gbc2, csr, cnt, ovfc, ovf);
  k_gather<<<(N_NODES * 64 + 255) / 256, 256, 0, stream>>>(xh, csr, cnt, xa);
  k_ovf2<<<1, 64, 0, stream>>>(ovf, ovfc, inputs, xa);
  const int mg = (N_NODES + 127) / 128;   // 782
  k_mfma<64, 0><<<mg, 256, 0, stream>>>(xa, wt1, b1, h1, nullptr);
  k_mfma<128, 0><<<mg, 256, 0, stream>>>(h1, wt2, b2, h2, nullptr);
  k_mfma<128, 1><<<mg, 256, 0, stream>>>(h2, wt3, b3, nullptr, hemb);
  k_stats<<<N_NODES / 32, 256, 0, stream>>>(hemb, batch, gsum, gsumq);
  k_finalize<<<N_GRAPHS, 128, 0, stream>>>(batch, gsum, gsumq, gms, gw, msc, scl, flat);
  k_apply<<<N_NODES / 32, 256, 0, stream>>>(hemb, batch, msc, scl, gb, flat);
  k_copy_i2f4<<<(2 * N_EDGES / 4 + 255) / 256, 256, 0, stream>>>((const int4*)ei, (float4*)o_ei, 2 * N_EDGES / 4);
  k_copy_f4<<<(N_EDGES * 2 + 255) / 256, 256, 0, stream>>>((const float4*)eattr, (float4*)o_ea, N_EDGES * 2);
  k_copy_i2f4<<<(N_NODES / 4 + 255) / 256, 256, 0, stream>>>((const int4*)batch, (float4*)o_b, N_NODES / 4);
}

// Round 14
// 317.805 us; speedup vs baseline: 1.6543x; 1.0341x over previous
//
#include <hip/hip_runtime.h>
#include <math.h>

#define N_NODES 100000
#define N_EDGES 1600000
#define N_GRAPHS 256
#define IN_F 64
#define H_F 128
#define GN_EPS 1e-5f
#define PAD 32
#define NBINS 8
#define LCAP 512
#define BINCAP (1 << 18)
#define NSUB 16
#define SUBW 782            // 16*782 = 12512 >= 12500
#define SBCAP 16384

typedef __attribute__((ext_vector_type(8))) short bf16x8;
typedef __attribute__((ext_vector_type(4))) float f32x4;

__device__ __forceinline__ float bf2f(unsigned short u) {
  return __uint_as_float(((unsigned int)u) << 16);
}
__device__ __forceinline__ unsigned short f2bf(float f) {
  unsigned int u = __float_as_uint(f);
  u += 0x7FFFu + ((u >> 16) & 1u);
  return (unsigned short)(u >> 16);
}

// ---- fused prologue: x->bf16 cast, W transpose->bf16, zero gsum/counters ----
#define PREP_XH   1600000                     // float4 units of x
#define PREP_GS   (PREP_XH + 16384)           // gsum+gsumq zero (float4)
#define PREP_WT   (PREP_GS + 40960)           // wt elements (u16)
#define PREP_CTR  (PREP_WT + 40)              // 160 ints of counters (int4)
__global__ __launch_bounds__(256) void k_prep(
    const float4* __restrict__ xin, const float* __restrict__ W1,
    const float* __restrict__ W2, const float* __restrict__ W3,
    ushort4* __restrict__ xh4, float4* __restrict__ gsum4,
    unsigned short* __restrict__ wt, int4* __restrict__ ctr4) {
  int i = blockIdx.x * 256 + threadIdx.x;
  if (i < PREP_XH) {
    float4 v = xin[i];
    ushort4 o;
    o.x = f2bf(v.x); o.y = f2bf(v.y); o.z = f2bf(v.z); o.w = f2bf(v.w);
    xh4[i] = o;
  } else if (i < PREP_GS) {
    gsum4[i - PREP_XH] = make_float4(0.f, 0.f, 0.f, 0.f);
  } else if (i < PREP_WT) {
    int j = i - PREP_GS;
    if (j < 8192) {                          // Wt1 [128][64]
      int n = j >> 6, k = j & 63;
      wt[j] = f2bf(W1[(size_t)k * H_F + n]);
    } else if (j < 24576) {                  // Wt2 [128][128]
      int jj = j - 8192;
      int n = jj >> 7, k = jj & 127;
      wt[j] = f2bf(W2[(size_t)k * H_F + n]);
    } else {                                 // Wt3 [128][128]
      int jj = j - 24576;
      int n = jj >> 7, k = jj & 127;
      wt[j] = f2bf(W3[(size_t)k * H_F + n]);
    }
  } else if (i < PREP_CTR) {
    ctr4[i - PREP_WT] = make_int4(0, 0, 0, 0);
  }
}

// ---- phase A: radix partition edges into 8 dst-range bins; u32-packed ----
__global__ __launch_bounds__(256) void k_bin(
    const int* __restrict__ src, const int* __restrict__ dst,
    unsigned int* __restrict__ binBuf, int* __restrict__ gbc) {
  __shared__ unsigned int ebuf[NBINS][LCAP];
  __shared__ int lcnt[NBINS];
  __shared__ int lbase[NBINS];
  const int t = threadIdx.x;
  if (t < NBINS) lcnt[t] = 0;
  __syncthreads();
  for (int e0 = blockIdx.x * 256; e0 < N_EDGES; e0 += gridDim.x * 256) {
    int e = e0 + t;
    if (e < N_EDGES) {
      int s = src[e], d = dst[e];
      int b = d / 12500;
      int p = atomicAdd(&lcnt[b], 1);
      ebuf[b][p] = ((unsigned)(d - b * 12500) << 17) | (unsigned)s;
    }
    __syncthreads();
    if (t < NBINS && lcnt[t] >= 256) lbase[t] = atomicAdd(&gbc[t], lcnt[t]);
    __syncthreads();
#pragma unroll
    for (int b = 0; b < NBINS; ++b) {
      int c = lcnt[b];
      if (c >= 256) {
        unsigned int* gp = binBuf + (size_t)b * BINCAP + lbase[b];
        for (int i = t; i < c; i += 256) gp[i] = ebuf[b][i];
      }
    }
    __syncthreads();
    if (t < NBINS && lcnt[t] >= 256) lcnt[t] = 0;
    __syncthreads();
  }
  if (t < NBINS && lcnt[t] > 0) lbase[t] = atomicAdd(&gbc[t], lcnt[t]);
  __syncthreads();
#pragma unroll
  for (int b = 0; b < NBINS; ++b) {
    int c = lcnt[b];
    if (c > 0) {
      unsigned int* gp = binBuf + (size_t)b * BINCAP + lbase[b];
      for (int i = t; i < c; i += 256) gp[i] = ebuf[b][i];
    }
  }
}

// ---- phase A2: split each parent bin into 16 sub-bins of 782 dsts ----
__global__ __launch_bounds__(256) void k_bin2(
    const unsigned int* __restrict__ binBuf, const int* __restrict__ gbc,
    unsigned int* __restrict__ binBuf2, int* __restrict__ gbc2) {
  __shared__ unsigned int ebuf[NSUB][LCAP];
  __shared__ int lcnt[NSUB];
  __shared__ int lbase[NSUB];
  const int t = threadIdx.x;
  const int p = blockIdx.x & 7;
  const int blk = blockIdx.x >> 3;
  const int nb = gbc[p];
  const unsigned int* buf = binBuf + (size_t)p * BINCAP;
  if (t < NSUB) lcnt[t] = 0;
  __syncthreads();
  for (int i0 = blk * 256; i0 < nb; i0 += 32 * 256) {
    int i = i0 + t;
    if (i < nb) {
      unsigned int e = buf[i];
      int dloc = (int)(e >> 17);
      int sub = dloc / SUBW;
      int p2 = atomicAdd(&lcnt[sub], 1);
      ebuf[sub][p2] = ((unsigned)(dloc - sub * SUBW) << 17) | (e & 131071u);
    }
    __syncthreads();
    if (t < NSUB && lcnt[t] >= 256)
      lbase[t] = atomicAdd(&gbc2[p * NSUB + t], lcnt[t]);
    __syncthreads();
#pragma unroll
    for (int b = 0; b < NSUB; ++b) {
      int c = lcnt[b];
      if (c >= 256) {
        unsigned int* gp = binBuf2 + (size_t)(p * NSUB + b) * SBCAP + lbase[b];
        for (int i2 = t; i2 < c; i2 += 256) gp[i2] = ebuf[b][i2];
      }
    }
    __syncthreads();
    if (t < NSUB && lcnt[t] >= 256) lcnt[t] = 0;
    __syncthreads();
  }
  if (t < NSUB && lcnt[t] > 0)
    lbase[t] = atomicAdd(&gbc2[p * NSUB + t], lcnt[t]);
  __syncthreads();
#pragma unroll
  for (int b = 0; b < NSUB; ++b) {
    int c = lcnt[b];
    if (c > 0) {
      unsigned int* gp = binBuf2 + (size_t)(p * NSUB + b) * SBCAP + lbase[b];
      for (int i2 = t; i2 < c; i2 += 256) gp[i2] = ebuf[b][i2];
    }
  }
}

// ---- phase B: per-sub-bin fill; csr slice assembled in LDS, dense copy-out ----
__global__ __launch_bounds__(256) void k_fill5(
    const unsigned int* __restrict__ binBuf2, const int* __restrict__ gbc2,
    int* __restrict__ csr, int* __restrict__ cnt,
    int* __restrict__ ovfc, int* __restrict__ ovf) {
  __shared__ int lcsr[SUBW * PAD];   // 100,096 B
  __shared__ int lcnt[SUBW];
  const int t = threadIdx.x;
  const int p = blockIdx.x & 7;
  const int sub = blockIdx.x >> 3;
  for (int j = t; j < SUBW; j += 256) lcnt[j] = 0;
  __syncthreads();
  const int n2 = gbc2[p * NSUB + sub];
  const unsigned int* buf = binBuf2 + (size_t)(p * NSUB + sub) * SBCAP;
  const int dbase = p * 12500 + sub * SUBW;
  for (int i = t; i < n2; i += 256) {
    unsigned int e = buf[i];
    int dloc2 = (int)(e >> 17);
    int s = (int)(e & 131071u);
    int pos = atomicAdd(&lcnt[dloc2], 1);
    if (pos < PAD) {
      lcsr[dloc2 * PAD + pos] = s;
    } else {
      int o = atomicAdd(ovfc, 1);
      ovf[2 * o] = s;
      ovf[2 * o + 1] = dbase + dloc2;
    }
  }
  __syncthreads();
  int rows = 12500 - sub * SUBW; if (rows > SUBW) rows = SUBW;
  int total4 = rows * (PAD / 4);
  int4* dst4 = (int4*)(csr + (size_t)dbase * PAD);
  const int4* src4 = (const int4*)lcsr;
  for (int i = t; i < total4; i += 256) dst4[i] = src4[i];
  for (int j = t; j < rows; j += 256)
    cnt[dbase + j] = lcnt[j] < PAD ? lcnt[j] : PAD;
}

// ---- gather: xa = x + sum_neighbors, bf16 out; 4-deep ILP ----
__global__ __launch_bounds__(256) void k_gather(
    const unsigned short* __restrict__ xh, const int* __restrict__ csr,
    const int* __restrict__ cnt, unsigned short* __restrict__ xa) {
  int wid = (blockIdx.x * 256 + threadIdx.x) >> 6;
  if (wid >= N_NODES) return;
  const int lane = threadIdx.x & 63;
  const int g = lane >> 4;
  const int fl = lane & 15;
  int deg = cnt[wid];
  int myE = csr[(size_t)wid * PAD + (lane & 31)];
  float s0 = 0.f, s1 = 0.f, s2 = 0.f, s3 = 0.f;
  int j = g;
  for (; j + 12 < deg; j += 16) {               // 4 loads in flight
    int sA = __shfl(myE, j);
    int sB = __shfl(myE, j + 4);
    int sC = __shfl(myE, j + 8);
    int sD = __shfl(myE, j + 12);
    ushort4 a = *(const ushort4*)&xh[(size_t)sA * IN_F + fl * 4];
    ushort4 b = *(const ushort4*)&xh[(size_t)sB * IN_F + fl * 4];
    ushort4 c = *(const ushort4*)&xh[(size_t)sC * IN_F + fl * 4];
    ushort4 d = *(const ushort4*)&xh[(size_t)sD * IN_F + fl * 4];
    s0 += bf2f(a.x) + bf2f(b.x) + bf2f(c.x) + bf2f(d.x);
    s1 += bf2f(a.y) + bf2f(b.y) + bf2f(c.y) + bf2f(d.y);
    s2 += bf2f(a.z) + bf2f(b.z) + bf2f(c.z) + bf2f(d.z);
    s3 += bf2f(a.w) + bf2f(b.w) + bf2f(c.w) + bf2f(d.w);
  }
  for (; j < deg; j += 4) {
    int sA = __shfl(myE, j);
    ushort4 a = *(const ushort4*)&xh[(size_t)sA * IN_F + fl * 4];
    s0 += bf2f(a.x); s1 += bf2f(a.y); s2 += bf2f(a.z); s3 += bf2f(a.w);
  }
  s0 += __shfl_xor(s0, 16); s1 += __shfl_xor(s1, 16);
  s2 += __shfl_xor(s2, 16); s3 += __shfl_xor(s3, 16);
  s0 += __shfl_xor(s0, 32); s1 += __shfl_xor(s1, 32);
  s2 += __shfl_xor(s2, 32); s3 += __shfl_xor(s3, 32);
  if (g == 0) {
    ushort4 self = *(const ushort4*)&xh[(size_t)wid * IN_F + fl * 4];
    s0 += bf2f(self.x); s1 += bf2f(self.y);
    s2 += bf2f(self.z); s3 += bf2f(self.w);
    ushort4 r;
    r.x = f2bf(s0); r.y = f2bf(s1); r.z = f2bf(s2); r.w = f2bf(s3);
    *(ushort4*)&xa[(size_t)wid * IN_F + fl * 4] = r;
  }
}

// ---- overflow fixup (deg > PAD; expected ~1 node); lane = feature, race-free ----
__global__ __launch_bounds__(64) void k_ovf2(
    const int* __restrict__ ovf, const int* __restrict__ ovfc,
    const float* __restrict__ x, unsigned short* __restrict__ xa) {
  int n = *ovfc;
  int f = threadIdx.x;
  for (int o = 0; o < n; ++o) {
    int s = ovf[2 * o], d = ovf[2 * o + 1];
    size_t idx = (size_t)d * IN_F + f;
    xa[idx] = f2bf(bf2f(xa[idx]) + x[(size_t)s * IN_F + f]);
  }
}

// ========== MFMA GEMM: LDS-free, 4 waves x 32 rows (2 row-tiles share B) ==========
template <int K, int OUTF32>
__global__ __launch_bounds__(256) void k_mfma(
    const unsigned short* __restrict__ A,
    const unsigned short* __restrict__ Wt,
    const float* __restrict__ bias,
    unsigned short* __restrict__ outh,
    float* __restrict__ outf) {
  const int t = threadIdx.x;
  const int lane = t & 63;
  const int wv = t >> 6;
  const int row16 = lane & 15;
  const int kg = lane >> 4;
  const int NS = K / 32;
  const long r0 = (long)blockIdx.x * 128 + wv * 32;
  long arow0 = r0 + row16;       if (arow0 > N_NODES - 1) arow0 = N_NODES - 1;
  long arow1 = r0 + 16 + row16;  if (arow1 > N_NODES - 1) arow1 = N_NODES - 1;
  bf16x8 a0[K / 32], a1[K / 32];
  {
    const unsigned short* ap0 = A + arow0 * K + kg * 8;
    const unsigned short* ap1 = A + arow1 * K + kg * 8;
#pragma unroll
    for (int s = 0; s < NS; ++s) {
      a0[s] = *(const bf16x8*)(ap0 + s * 32);
      a1[s] = *(const bf16x8*)(ap1 + s * 32);
    }
  }
  f32x4 acc0[8], acc1[8];
#pragma unroll
  for (int n = 0; n < 8; ++n) {
    acc0[n] = (f32x4){0.f, 0.f, 0.f, 0.f};
    acc1[n] = (f32x4){0.f, 0.f, 0.f, 0.f};
  }
  const unsigned short* wp = Wt + (size_t)row16 * K + kg * 8;
#pragma unroll
  for (int n = 0; n < 8; ++n) {
    const unsigned short* wpn = wp + (size_t)n * 16 * K;
    bf16x8 b[K / 32];
#pragma unroll
    for (int s = 0; s < NS; ++s) b[s] = *(const bf16x8*)(wpn + s * 32);
#pragma unroll
    for (int s = 0; s < NS; ++s) {
      acc0[n] = __builtin_amdgcn_mfma_f32_16x16x32_bf16(a0[s], b[s], acc0[n], 0, 0, 0);
      acc1[n] = __builtin_amdgcn_mfma_f32_16x16x32_bf16(a1[s], b[s], acc1[n], 0, 0, 0);
    }
  }
#pragma unroll
  for (int n = 0; n < 8; ++n) {
    int col = n * 16 + row16;
    float bv = bias[col];
#pragma unroll
    for (int r = 0; r < 4; ++r) {
      long row0 = r0 + kg * 4 + r;
      long row1 = r0 + 16 + kg * 4 + r;
      if (row0 < N_NODES) {
        float v = fmaxf(acc0[n][r] + bv, 0.f);
        if (OUTF32) outf[row0 * H_F + col] = v;
        else        outh[row0 * H_F + col] = f2bf(v);
      }
      if (row1 < N_NODES) {
        float v = fmaxf(acc1[n][r] + bv, 0.f);
        if (OUTF32) outf[row1 * H_F + col] = v;
        else        outh[row1 * H_F + col] = f2bf(v);
      }
    }
  }
}

// ---- standalone GraphNorm stats over h3 fp32 (32-row blocks) ----
__global__ __launch_bounds__(256) void k_stats(
    const float* __restrict__ h, const int* __restrict__ batch,
    float* __restrict__ gsum, float* __restrict__ gsumsq) {
  __shared__ __align__(16) float4 sred[256];
  __shared__ __align__(16) float4 qred[256];
  const int t = threadIdx.x;
  const int m0 = blockIdx.x * 32;
  const int tm0 = (t >> 5) * 4, tn0 = (t & 31) * 4;
  const int rg = t >> 5, fq = t & 31;
  float4 v[4];
#pragma unroll
  for (int i = 0; i < 4; ++i)
    v[i] = *(const float4*)&h[(size_t)(m0 + tm0 + i) * H_F + tn0];
  const int glo = batch[m0];
  const int ghi = batch[m0 + 31];
  if (glo == ghi) {
    float4 s = {0,0,0,0}, q = {0,0,0,0};
#pragma unroll
    for (int i = 0; i < 4; ++i) {
      s.x += v[i].x; s.y += v[i].y; s.z += v[i].z; s.w += v[i].w;
      q.x += v[i].x * v[i].x; q.y += v[i].y * v[i].y;
      q.z += v[i].z * v[i].z; q.w += v[i].w * v[i].w;
    }
    sred[rg * 32 + fq] = s;
    qred[rg * 32 + fq] = q;
    __syncthreads();
    if (rg == 0) {
      float4 S = {0,0,0,0}, Q = {0,0,0,0};
#pragma unroll
      for (int j = 0; j < 8; ++j) {
        float4 a0 = sred[j * 32 + fq], b0 = qred[j * 32 + fq];
        S.x += a0.x; S.y += a0.y; S.z += a0.z; S.w += a0.w;
        Q.x += b0.x; Q.y += b0.y; Q.z += b0.z; Q.w += b0.w;
      }
      float* ps = &gsum[(size_t)glo * H_F + fq * 4];
      float* pq = &gsumsq[(size_t)glo * H_F + fq * 4];
      unsafeAtomicAdd(ps + 0, S.x); unsafeAtomicAdd(ps + 1, S.y);
      unsafeAtomicAdd(ps + 2, S.z); unsafeAtomicAdd(ps + 3, S.w);
      unsafeAtomicAdd(pq + 0, Q.x); unsafeAtomicAdd(pq + 1, Q.y);
      unsafeAtomicAdd(pq + 2, Q.z); unsafeAtomicAdd(pq + 3, Q.w);
    }
  } else {
    int gcur = batch[m0 + tm0];
    float4 s = {0,0,0,0}, q = {0,0,0,0};
#pragma unroll
    for (int i = 0; i < 4; ++i) {
      int g = batch[m0 + tm0 + i];
      if (g != gcur) {
        float* ps = &gsum[(size_t)gcur * H_F + tn0];
        float* pq = &gsumsq[(size_t)gcur * H_F + tn0];
        unsafeAtomicAdd(ps + 0, s.x); unsafeAtomicAdd(ps + 1, s.y);
        unsafeAtomicAdd(ps + 2, s.z); unsafeAtomicAdd(ps + 3, s.w);
        unsafeAtomicAdd(pq + 0, q.x); unsafeAtomicAdd(pq + 1, q.y);
        unsafeAtomicAdd(pq + 2, q.z); unsafeAtomicAdd(pq + 3, q.w);
        s = make_float4(0, 0, 0, 0); q = make_float4(0, 0, 0, 0);
        gcur = g;
      }
      s.x += v[i].x; s.y += v[i].y; s.z += v[i].z; s.w += v[i].w;
      q.x += v[i].x * v[i].x; q.y += v[i].y * v[i].y;
      q.z += v[i].z * v[i].z; q.w += v[i].w * v[i].w;
    }
    float* ps = &gsum[(size_t)gcur * H_F + tn0];
    float* pq = &gsumsq[(size_t)gcur * H_F + tn0];
    unsafeAtomicAdd(ps + 0, s.x); unsafeAtomicAdd(ps + 1, s.y);
    unsafeAtomicAdd(ps + 2, s.z); unsafeAtomicAdd(ps + 3, s.w);
    unsafeAtomicAdd(pq + 0, q.x); unsafeAtomicAdd(pq + 1, q.y);
    unsafeAtomicAdd(pq + 2, q.z); unsafeAtomicAdd(pq + 3, q.w);
  }
}

// ---- finalize: per (graph,feature) shift/scale; init flat = -INF ----
__global__ __launch_bounds__(128) void k_finalize(
    const int* __restrict__ batch, const float* __restrict__ gsum,
    const float* __restrict__ gsumsq, const float* __restrict__ gms,
    const float* __restrict__ gw, float* __restrict__ msc,
    float* __restrict__ scale, float* __restrict__ flat) {
  const int g = blockIdx.x;
  const int f = threadIdx.x;
  __shared__ int sb[2];
  if (f < 2) {
    int target = g + f;
    int lo = 0, hi = N_NODES;
    while (lo < hi) { int mid = (lo + hi) >> 1; if (batch[mid] < target) lo = mid + 1; else hi = mid; }
    sb[f] = lo;
  }
  __syncthreads();
  float c = fmaxf((float)(sb[1] - sb[0]), 1.0f);
  float mean = gsum[(size_t)g * H_F + f] / c;
  float ms = mean * gms[f];
  float var = gsumsq[(size_t)g * H_F + f] / c - 2.0f * ms * mean + ms * ms;
  var = fmaxf(var, 0.0f);
  msc[(size_t)g * H_F + f] = ms;
  scale[(size_t)g * H_F + f] = gw[f] * rsqrtf(var + GN_EPS);
  flat[(size_t)g * H_F + f] = -INFINITY;
}

// ---- apply: h = relu((h - msc)*scale + gb); flat = segment max ----
__global__ __launch_bounds__(256) void k_apply(
    float* __restrict__ h, const int* __restrict__ batch,
    const float* __restrict__ msc, const float* __restrict__ scale,
    const float* __restrict__ gb, float* __restrict__ flat) {
  const int t = threadIdx.x;
  const int rg = t >> 5, fq = t & 31;
  const int m0 = blockIdx.x * 32;
  const int r0 = m0 + rg * 4;
  const float4 bb = *(const float4*)&gb[fq * 4];
  const int glo = batch[m0], ghi = batch[m0 + 31];
  __shared__ __align__(16) float4 mred[8][32];
  if (glo == ghi) {
    const float4 m = *(const float4*)&msc[(size_t)glo * H_F + fq * 4];
    const float4 sc = *(const float4*)&scale[(size_t)glo * H_F + fq * 4];
    float4 mx = {-INFINITY, -INFINITY, -INFINITY, -INFINITY};
#pragma unroll
    for (int i = 0; i < 4; ++i) {
      size_t idx = (size_t)(r0 + i) * H_F + fq * 4;
      float4 v = *(const float4*)&h[idx];
      v.x = fmaxf((v.x - m.x) * sc.x + bb.x, 0.f);
      v.y = fmaxf((v.y - m.y) * sc.y + bb.y, 0.f);
      v.z = fmaxf((v.z - m.z) * sc.z + bb.z, 0.f);
      v.w = fmaxf((v.w - m.w) * sc.w + bb.w, 0.f);
      *(float4*)&h[idx] = v;
      mx.x = fmaxf(mx.x, v.x); mx.y = fmaxf(mx.y, v.y);
      mx.z = fmaxf(mx.z, v.z); mx.w = fmaxf(mx.w, v.w);
    }
    mred[rg][fq] = mx;
    __syncthreads();
    if (rg == 0) {
#pragma unroll
      for (int j = 1; j < 8; ++j) {
        float4 a = mred[j][fq];
        mx.x = fmaxf(mx.x, a.x); mx.y = fmaxf(mx.y, a.y);
        mx.z = fmaxf(mx.z, a.z); mx.w = fmaxf(mx.w, a.w);
      }
      int* pf = (int*)&flat[(size_t)glo * H_F + fq * 4];
      atomicMax(pf + 0, __float_as_int(mx.x));
      atomicMax(pf + 1, __float_as_int(mx.y));
      atomicMax(pf + 2, __float_as_int(mx.z));
      atomicMax(pf + 3, __float_as_int(mx.w));
    }
  } else {
    int gcur = batch[r0];
    float4 mm = *(const float4*)&msc[(size_t)gcur * H_F + fq * 4];
    float4 ss = *(const float4*)&scale[(size_t)gcur * H_F + fq * 4];
    float4 mx = {-INFINITY, -INFINITY, -INFINITY, -INFINITY};
#pragma unroll
    for (int i = 0; i < 4; ++i) {
      int g = batch[r0 + i];
      if (g != gcur) {
        int* pf = (int*)&flat[(size_t)gcur * H_F + fq * 4];
        atomicMax(pf + 0, __float_as_int(mx.x));
        atomicMax(pf + 1, __float_as_int(mx.y));
        atomicMax(pf + 2, __float_as_int(mx.z));
        atomicMax(pf + 3, __float_as_int(mx.w));
        mx = make_float4(-INFINITY, -INFINITY, -INFINITY, -INFINITY);
        gcur = g;
        mm = *(const float4*)&msc[(size_t)gcur * H_F + fq * 4];
        ss = *(const float4*)&scale[(size_t)gcur * H_F + fq * 4];
      }
      size_t idx = (size_t)(r0 + i) * H_F + fq * 4;
      float4 v = *(const float4*)&h[idx];
      v.x = fmaxf((v.x - mm.x) * ss.x + bb.x, 0.f);
      v.y = fmaxf((v.y - mm.y) * ss.y + bb.y, 0.f);
      v.z = fmaxf((v.z - mm.z) * ss.z + bb.z, 0.f);
      v.w = fmaxf((v.w - mm.w) * ss.w + bb.w, 0.f);
      *(float4*)&h[idx] = v;
      mx.x = fmaxf(mx.x, v.x); mx.y = fmaxf(mx.y, v.y);
      mx.z = fmaxf(mx.z, v.z); mx.w = fmaxf(mx.w, v.w);
    }
    int* pf = (int*)&flat[(size_t)gcur * H_F + fq * 4];
    atomicMax(pf + 0, __float_as_int(mx.x));
    atomicMax(pf + 1, __float_as_int(mx.y));
    atomicMax(pf + 2, __float_as_int(mx.z));
    atomicMax(pf + 3, __float_as_int(mx.w));
    __syncthreads();
  }
}

// ---- merged passthrough copies: ei, eattr, batch in one kernel ----
#define CP_EI  800000                          // int4 units of edge_index
#define CP_EA  (CP_EI + 3200000)               // float4 units of edge_attr
#define CP_B   (CP_EA + 25000)                 // int4 units of batch
__global__ __launch_bounds__(256) void k_copyall(
    const int4* __restrict__ ei4, const float4* __restrict__ ea4,
    const int4* __restrict__ b4, float4* __restrict__ o_ei4,
    float4* __restrict__ o_ea4, float4* __restrict__ o_b4) {
  int i = blockIdx.x * 256 + threadIdx.x;
  if (i < CP_EI) {
    int4 v = ei4[i];
    o_ei4[i] = make_float4((float)v.x, (float)v.y, (float)v.z, (float)v.w);
  } else if (i < CP_EA) {
    int j = i - CP_EI;
    o_ea4[j] = ea4[j];
  } else if (i < CP_B) {
    int j = i - CP_EA;
    int4 v = b4[j];
    o_b4[j] = make_float4((float)v.x, (float)v.y, (float)v.z, (float)v.w);
  }
}

extern "C" void kernel_launch(void* const* d_in, const int* in_sizes, int n_in,
                              void* d_out, int out_size, void* d_ws, size_t ws_size,
                              hipStream_t stream) {
  const float* inputs = (const float*)d_in[0];
  const int*   ei     = (const int*)d_in[1];
  const int*   batch  = (const int*)d_in[2];
  const float* eattr  = (const float*)d_in[3];
  const float* W1 = (const float*)d_in[4];
  const float* b1 = (const float*)d_in[5];
  const float* W2 = (const float*)d_in[6];
  const float* b2 = (const float*)d_in[7];
  const float* W3 = (const float*)d_in[8];
  const float* b3 = (const float*)d_in[9];
  const float* gw  = (const float*)d_in[10];
  const float* gb  = (const float*)d_in[11];
  const float* gms = (const float*)d_in[12];

  float* out = (float*)d_out;
  float* hemb  = out;                          // [100000,128] fp32
  float* flat  = out + 12800000;               // [256,128]
  float* o_ei  = out + 12832768;               // [2,1600000]
  float* o_ea  = out + 16032768;               // [1600000,8]
  float* o_b   = out + 28832768;               // [100000]

  unsigned int*   binBuf  = (unsigned int*)hemb;
  unsigned int*   binBuf2 = (unsigned int*)(hemb + 2100000);
  unsigned short* xh = (unsigned short*)(hemb + 4200000);
  unsigned short* xa = (unsigned short*)(hemb + 7600000);
  int*            csr = (int*)o_ea;
  unsigned short* h2  = (unsigned short*)o_ea;
  unsigned short* h1  = (unsigned short*)(o_ea + 6400000);
  int*   cnt   = (int*)o_ei;                    // [N_NODES] (fully written by k_fill5)
  int*   ovfc  = (int*)o_ei + 100000;           // [1] ... ctr block of 160 ints
  int*   gbc   = (int*)o_ei + 100008;           // [8]
  int*   gbc2  = (int*)o_ei + 100016;           // [128]
  int*   ovf   = (int*)o_ei + 100160;           // pairs, tiny
  float* gsum  = o_ei + 200000;
  float* gsumq = o_ei + 232768;
  float* msc   = o_ei + 265536;
  float* scl   = o_ei + 298304;
  unsigned short* wt  = (unsigned short*)(o_ei + 350000);
  unsigned short* wt1 = wt;
  unsigned short* wt2 = wt + 8192;
  unsigned short* wt3 = wt + 24576;

  // fused prologue (cast + W transpose + zero gsum/gsumq + zero counters)
  k_prep<<<(PREP_CTR + 255) / 256, 256, 0, stream>>>(
      (const float4*)inputs, W1, W2, W3, (ushort4*)xh, (float4*)gsum, wt,
      (int4*)ovfc);
  k_bin<<<512, 256, 0, stream>>>(ei, ei + N_EDGES, binBuf, gbc);
  k_bin2<<<256, 256, 0, stream>>>(binBuf, gbc, binBuf2, gbc2);
  k_fill5<<<NBINS * NSUB, 256, 0, stream>>>(binBuf2, gbc2, csr, cnt, ovfc, ovf);
  k_gather<<<(N_NODES * 64 + 255) / 256, 256, 0, stream>>>(xh, csr, cnt, xa);
  k_ovf2<<<1, 64, 0, stream>>>(ovf, ovfc, inputs, xa);
  const int mg = (N_NODES + 127) / 128;   // 782
  k_mfma<64, 0><<<mg, 256, 0, stream>>>(xa, wt1, b1, h1, nullptr);
  k_mfma<128, 0><<<mg, 256, 0, stream>>>(h1, wt2, b2, h2, nullptr);
  k_mfma<128, 1><<<mg, 256, 0, stream>>>(h2, wt3, b3, nullptr, hemb);
  k_stats<<<N_NODES / 32, 256, 0, stream>>>(hemb, batch, gsum, gsumq);
  k_finalize<<<N_GRAPHS, 128, 0, stream>>>(batch, gsum, gsumq, gms, gw, msc, scl, flat);
  k_apply<<<N_NODES / 32, 256, 0, stream>>>(hemb, batch, msc, scl, gb, flat);
  k_copyall<<<(CP_B + 255) / 256, 256, 0, stream>>>(
      (const int4*)ei, (const float4*)eattr, (const int4*)batch,
      (float4*)o_ei, (float4*)o_ea, (float4*)o_b);
}